// Round 11
// baseline (209.127 us; speedup 1.0000x reference)
//
#include <hip/hip_runtime.h>
#include <stdint.h>

// Problem constants
#define B_    2
#define NQ_   1024
#define NKV_  4096
#define DQ_   1024
#define H_    16
#define DH_   64
#define INNER_ 1024

typedef unsigned short u16;
typedef uint32_t u32;
typedef __bf16 bf16x8 __attribute__((ext_vector_type(8)));
typedef float  f32x4  __attribute__((ext_vector_type(4)));

__device__ __forceinline__ u16 f2bf(float x) {           // RNE
  union { float f; uint32_t u; } v; v.f = x;
  uint32_t r = v.u + 0x7FFFu + ((v.u >> 16) & 1u);
  return (u16)(r >> 16);
}
__device__ __forceinline__ u32 pack2(float a, float b) { // RNE pair
  return (u32)f2bf(a) | ((u32)f2bf(b) << 16);
}
__device__ __forceinline__ u32 pack2rn(float a, float b) { // fast RN via v_perm (3 VALU)
  union { float f; u32 u; } x, y; x.f = a; y.f = b;
  return __builtin_amdgcn_perm(y.u + 0x8000u, x.u + 0x8000u, 0x07060302u);
}
__device__ __forceinline__ float bf2f(u16 s) {
  union { float f; uint32_t u; } v; v.u = ((uint32_t)s) << 16; return v.f;
}

// async global->LDS, 16B/lane; lds base wave-uniform, hw adds lane*16
__device__ __forceinline__ void gload16(const void* g, void* l) {
  __builtin_amdgcn_global_load_lds((const __attribute__((address_space(1))) void*)g,
                                   (__attribute__((address_space(3))) void*)l,
                                   16, 0, 0);
}

// ---------------- fused prep: casts + weight transposes in ONE dispatch -----------------
// blocks [0,640): fat casts (16 x float4 per thread; x=128 blocks, ctx=512);
// [640,896): Wq^T 64x64 tiles; [896,1408): Wkv^T; [1408,1664): Wout^T.
// 64x64 transpose: 256B coalesced loads, packed-u32 stores in 128B runs, LDS [64][65].
__global__ __launch_bounds__(256) void prep(const float* __restrict__ x,
                                            const float* __restrict__ ctx,
                                            const float* __restrict__ Wq,
                                            const float* __restrict__ Wkv,
                                            const float* __restrict__ Wout,
                                            u16* __restrict__ xb,
                                            u16* __restrict__ ctxb,
                                            u16* __restrict__ WqT,
                                            u16* __restrict__ WkvT,
                                            u16* __restrict__ WoutT) {
  int bid = blockIdx.x;
  if (bid < 640) {                         // elementwise cast, 64 elems/thread
    const float* src; u16* dst; int fbase;  // float4 units
    if (bid < 128) { src = x;   dst = xb;   fbase = bid * 4096; }
    else           { src = ctx; dst = ctxb; fbase = (bid - 128) * 4096; }
#pragma unroll
    for (int u = 0; u < 16; ++u) {
      int i = (fbase + u * 256 + threadIdx.x) * 4;
      float4 v = *(const float4*)(src + i);
      uint2 o; o.x = pack2(v.x, v.y); o.y = pack2(v.z, v.w);
      *(uint2*)(dst + i) = o;
    }
    return;
  }
  // transpose+cast W[K][N] -> Wt[N][K], 64x64 tiles
  __shared__ float tile[64][65];           // 16.6 KB
  const float* W; u16* Wt; int K, N, local, ntm;  // ntm = n-tiles mask
  int b2 = bid - 640;
  if (b2 < 256)      { W = Wq;   Wt = WqT;   K = 1024; N = 1024; local = b2;       ntm = 15; }
  else if (b2 < 768) { W = Wkv;  Wt = WkvT;  K = 1024; N = 2048; local = b2 - 256; ntm = 31; }
  else               { W = Wout; Wt = WoutT; K = 1024; N = 1024; local = b2 - 768; ntm = 15; }
  int n0 = (local & ntm) * 64;
  int k0 = (local > ntm ? local >> (ntm == 15 ? 4 : 5) : 0) * 64;
  // (branchless form of local>>log2(ntiles); recompute cleanly:)
  k0 = (ntm == 15) ? (local >> 4) * 64 : (local >> 5) * 64;
  int tx = threadIdx.x & 63, ty = threadIdx.x >> 6;    // 64 x 4
  for (int i = ty; i < 64; i += 4)
    tile[i][tx] = W[(size_t)(k0 + i) * N + n0 + tx];
  __syncthreads();
  // packed u32 stores: 32 k-pairs x 8 rows per pass -> two 128B runs per wave
  int tx2 = threadIdx.x & 31, ty2 = threadIdx.x >> 5;  // 32 x 8
  for (int j = ty2; j < 64; j += 8)
    *(u32*)&Wt[(size_t)(n0 + j) * K + k0 + tx2 * 2] =
        pack2(tile[tx2 * 2][j], tile[tx2 * 2 + 1][j]);
}

// ---------------- kv projection: 256x256 / BK=64 / FAITHFUL 8-phase schedule ------------
// R8-proven. 2 K-steps per iteration; counted vmcnt(6) only at ph4/ph8; stage ledger
// WAR-safe; every wait's targets >=4 phases old. Epilogues round-1 proven.
__global__ __launch_bounds__(512, 2) void kv_gemm(const u16* __restrict__ ctxb,
                                                  const u16* __restrict__ WkvT,
                                                  u16* __restrict__ kb,
                                                  u16* __restrict__ vTb) {
  __shared__ __align__(16) u16 As[2][256 * 64];   // 64 KiB
  __shared__ __align__(16) u16 Bs[2][256 * 64];   // 64 KiB
  const int tid = threadIdx.x;
  const int lane = tid & 63;
  const int w = tid >> 6;                 // 0..7
  const int wr = w >> 2, wc = w & 3;      // 2 x 4 waves -> wave panel 128M x 64N
  const int l15 = lane & 15, quad = lane >> 4;
  const int K = 1024;

  // XCD-chunked bijective swizzle
  int bid = blockIdx.x;
  int wgid = (bid & 7) * 32 + (bid >> 3);
  const int tm = wgid >> 3, tn = wgid & 7;
  const int m0 = tm * 256, n0 = tn * 256;
  const u16* Ag = ctxb + (size_t)m0 * K;
  const u16* Bg = WkvT + (size_t)n0 * K;

  // per-thread stage source offsets (u16 units): row-reorder + chunk XOR pre-swizzle
  size_t offA[2][2], offB[2][2];
#pragma unroll
  for (int ah = 0; ah < 2; ++ah)
#pragma unroll
    for (int p = 0; p < 2; ++p) {
      int c = p * 512 + (w << 6) + lane;  // chunk id within 16 KiB region
      int s = ah * 128 + (c >> 3);        // LDS slot (reordered row)
      int col = ((c & 7) ^ (s & 7)) << 3; // pre-swizzled source column (bf16)
      int rA = ((s >> 6) & 1) * 128 + ((s >> 7) & 1) * 64 + (s & 63);
      int rB = ((s >> 5) & 3) * 64 + ((s >> 7) & 1) * 32 + (s & 31);
      offA[ah][p] = (size_t)rA * 1024 + col;
      offB[ah][p] = (size_t)rB * 1024 + col;
    }

#define STAGE_A(bufi, ah, kk) do { \
    gload16(Ag + offA[ah][0] + (kk), &As[bufi][(ah) * 8192 + (w << 9)]); \
    gload16(Ag + offA[ah][1] + (kk), &As[bufi][(ah) * 8192 + 4096 + (w << 9)]); \
  } while (0)
#define STAGE_B(bufi, bh, kk) do { \
    gload16(Bg + offB[bh][0] + (kk), &Bs[bufi][(bh) * 8192 + (w << 9)]); \
    gload16(Bg + offB[bh][1] + (kk), &Bs[bufi][(bh) * 8192 + 4096 + (w << 9)]); \
  } while (0)
#define LDA2(dst, i8, bufi) do { \
    const int _s = ((i8) >> 2) * 128 + wr * 64 + ((i8) & 3) * 16 + l15; \
    const u16* _p = &As[bufi][_s * 64]; const int _x = _s & 7; \
    dst[0] = *(const bf16x8*)&_p[(quad ^ _x) << 3]; \
    dst[1] = *(const bf16x8*)&_p[((quad + 4) ^ _x) << 3]; \
  } while (0)
#define LDB2(dst, j, bufi) do { \
    const int _s = ((j) >> 1) * 128 + wc * 32 + ((j) & 1) * 16 + l15; \
    const u16* _p = &Bs[bufi][_s * 64]; const int _x = _s & 7; \
    dst[0] = *(const bf16x8*)&_p[(quad ^ _x) << 3]; \
    dst[1] = *(const bf16x8*)&_p[((quad + 4) ^ _x) << 3]; \
  } while (0)
#define MF(i0, j0, bb) do { \
    _Pragma("unroll") \
    for (int _i = 0; _i < 4; ++_i) { \
      acc[(i0) + _i][(j0)    ] = __builtin_amdgcn_mfma_f32_16x16x32_bf16(a[_i][0], bb[0][0], acc[(i0) + _i][(j0)    ], 0, 0, 0); \
      acc[(i0) + _i][(j0)    ] = __builtin_amdgcn_mfma_f32_16x16x32_bf16(a[_i][1], bb[0][1], acc[(i0) + _i][(j0)    ], 0, 0, 0); \
      acc[(i0) + _i][(j0) + 1] = __builtin_amdgcn_mfma_f32_16x16x32_bf16(a[_i][0], bb[1][0], acc[(i0) + _i][(j0) + 1], 0, 0, 0); \
      acc[(i0) + _i][(j0) + 1] = __builtin_amdgcn_mfma_f32_16x16x32_bf16(a[_i][1], bb[1][1], acc[(i0) + _i][(j0) + 1], 0, 0, 0); \
    } \
  } while (0)
#define BAR()   __builtin_amdgcn_s_barrier()
#define LGKM0() asm volatile("s_waitcnt lgkmcnt(0)" ::: "memory")

  f32x4 acc[8][4] = {};
  bf16x8 a[4][2], b[2][2], c2[2][2];

  // prologue: step0 full (Aa,Ba,Bb,Ab) + step1 trio (Aa,Ba,Bb) = 14 loads
  STAGE_A(0, 0, 0);
  STAGE_B(0, 0, 0);
  STAGE_B(0, 1, 0);
  STAGE_A(0, 1, 0);
  STAGE_A(1, 0, 64);
  STAGE_B(1, 0, 64);
  STAGE_B(1, 1, 64);
  asm volatile("s_waitcnt vmcnt(6)" ::: "memory");   // step0's 8 loads complete
  BAR();

#define HALF(bufi, kAb, kNext, STG, WMID, WEND) do { \
    LDB2(b[0], 0, bufi); LDB2(b[1], 1, bufi); \
    LDA2(a[0], 0, bufi); LDA2(a[1], 1, bufi); LDA2(a[2], 2, bufi); LDA2(a[3], 3, bufi); \
    if (kAb >= 0) STAGE_A((bufi) ^ 1, 1, kAb); \
    BAR(); LGKM0(); \
    __builtin_amdgcn_s_setprio(1); MF(0, 0, b); __builtin_amdgcn_s_setprio(0); \
    BAR(); \
    LDB2(c2[0], 2, bufi); LDB2(c2[1], 3, bufi); \
    if (STG) STAGE_A(bufi, 0, kNext); \
    BAR(); LGKM0(); \
    __builtin_amdgcn_s_setprio(1); MF(0, 2, c2); __builtin_amdgcn_s_setprio(0); \
    BAR(); \
    LDA2(a[0], 4, bufi); LDA2(a[1], 5, bufi); LDA2(a[2], 6, bufi); LDA2(a[3], 7, bufi); \
    if (STG) STAGE_B(bufi, 0, kNext); \
    BAR(); LGKM0(); \
    __builtin_amdgcn_s_setprio(1); MF(4, 0, b); __builtin_amdgcn_s_setprio(0); \
    BAR(); \
    if (STG) STAGE_B(bufi, 1, kNext); \
    BAR(); \
    __builtin_amdgcn_s_setprio(1); MF(4, 2, c2); __builtin_amdgcn_s_setprio(0); \
    WMID; \
    BAR(); \
  } while (0)

  for (int i = 0; i < 7; ++i) {
    const int k2 = i * 128;
    HALF(0, k2 + 64, k2 + 128, 1,
         asm volatile("s_waitcnt vmcnt(6)" ::: "memory"), );
    HALF(1, k2 + 128, k2 + 192, 1,
         asm volatile("s_waitcnt vmcnt(6)" ::: "memory"), );
  }
  HALF(0, 960, 0, 0,
       asm volatile("s_waitcnt vmcnt(0)" ::: "memory"), );
  HALF(1, -1, 0, 0, , );

#undef HALF
#undef BAR
#undef LGKM0

  // epilogue (round-1 proven): tn<4 -> K row-major, tn>=4 -> V transposed scatter
  if (tn < 4) {
#pragma unroll
    for (int i8 = 0; i8 < 8; ++i8)
#pragma unroll
      for (int j = 0; j < 4; ++j) {
        int col = n0 + wc * 64 + j * 16 + l15;
#pragma unroll
        for (int r = 0; r < 4; ++r) {
          int row = m0 + wr * 128 + i8 * 16 + quad * 4 + r;
          kb[(size_t)row * 1024 + col] = f2bf(acc[i8][j][r]);
        }
      }
  } else {
    const int bb_ = m0 >> 12;
#pragma unroll
    for (int i8 = 0; i8 < 8; ++i8) {
      int kvr = (m0 & 4095) + wr * 128 + i8 * 16 + quad * 4;
#pragma unroll
      for (int j = 0; j < 4; ++j) {
        int c = (n0 - 1024) + wc * 64 + j * 16 + l15;
        int h = c >> 6, dh = c & 63;
        uint2 st;
        st.x = pack2(acc[i8][j][0], acc[i8][j][1]);
        st.y = pack2(acc[i8][j][2], acc[i8][j][3]);
        *(uint2*)&vTb[((size_t)((bb_ * 16 + h) * 64 + dh)) * NKV_ + kvr] = st;
      }
    }
  }
#undef STAGE_A
#undef STAGE_B
#undef LDA2
#undef LDB2
#undef MF
}

// ---------------- out-proj GEMM: 64x128 tiles, tri-buffered counted-vmcnt pipeline ------
__global__ __launch_bounds__(256) void out_gemm(const u16* __restrict__ A,
                                                const u16* __restrict__ Bt,
                                                float* __restrict__ Cout,
                                                const float* __restrict__ bias) {
  __shared__ __align__(16) u16 As[3][64 * 32];    // 12 KB
  __shared__ __align__(16) u16 Bs[3][128 * 32];   // 24 KB
  const int tid = threadIdx.x;
  const int lane = tid & 63;
  const int w = tid >> 6;
  const int wr = w >> 1, wc = w & 1;           // wave covers 32M x 64N
  const int l15 = lane & 15, quad = lane >> 4;
  const int unit = blockIdx.x;
  const int m0 = (unit >> 3) * 64, n0 = (unit & 7) * 128;
  const int K = 1024, N = 1024;

  const u16* Ab = A + (size_t)m0 * K;
  const u16* Bb = Bt + (size_t)n0 * K;
  f32x4 acc[2][4] = {};

  const int ar = tid >> 2, ac = (tid & 3) << 3;          // A: 256 chunks, 1/thread
  const int q1 = w * 64 + lane, q2 = q1 + 256;           // B: 512 chunks, 2/thread
  const int br1 = q1 >> 2, bc1 = (q1 & 3) << 3;
  const int br2 = q2 >> 2, bc2 = (q2 & 3) << 3;

#define STG(bi, k0) do { \
    gload16(Ab + (size_t)ar * K + (k0) + ac, &As[bi][w * 512]); \
    gload16(Bb + (size_t)br1 * K + (k0) + bc1, &Bs[bi][w * 512]); \
    gload16(Bb + (size_t)br2 * K + (k0) + bc2, &Bs[bi][2048 + w * 512]); \
  } while (0)

  STG(0, 0);
  STG(1, 32);
  asm volatile("s_waitcnt vmcnt(3)" ::: "memory");   // STG(0) complete, STG(1) in flight
  __builtin_amdgcn_s_barrier();

  for (int it = 0; it < 32; ++it) {
    const int cur = it % 3;
    bf16x8 af[2], bfr[4];
#pragma unroll
    for (int i = 0; i < 2; ++i)
      af[i] = *(const bf16x8*)&As[cur][(wr * 32 + i * 16 + l15) * 32 + quad * 8];
#pragma unroll
    for (int j = 0; j < 4; ++j)
      bfr[j] = *(const bf16x8*)&Bs[cur][(wc * 64 + j * 16 + l15) * 32 + quad * 8];
    if (it + 2 < 32) STG((it + 2) % 3, (it + 2) * 32);
    __builtin_amdgcn_s_barrier();
    asm volatile("s_waitcnt lgkmcnt(0)" ::: "memory");
    __builtin_amdgcn_s_setprio(1);
#pragma unroll
    for (int i = 0; i < 2; ++i)
#pragma unroll
      for (int j = 0; j < 4; ++j)
        acc[i][j] = __builtin_amdgcn_mfma_f32_16x16x32_bf16(af[i], bfr[j], acc[i][j], 0, 0, 0);
    __builtin_amdgcn_s_setprio(0);
    if (it + 2 < 32)      { asm volatile("s_waitcnt vmcnt(3)" ::: "memory"); }
    else if (it + 2 == 32){ asm volatile("s_waitcnt vmcnt(0)" ::: "memory"); }
    __builtin_amdgcn_s_barrier();
  }
#undef STG

#pragma unroll
  for (int i = 0; i < 2; ++i)
#pragma unroll
    for (int j = 0; j < 4; ++j) {
      int col = n0 + wc * 64 + j * 16 + l15;
      float bv = bias[col];
#pragma unroll
      for (int r = 0; r < 4; ++r) {
        int row = m0 + wr * 32 + i * 16 + quad * 4 + r;
        Cout[(size_t)row * N + col] = acc[i][j][r] + bv;
      }
    }
}

// ---------------- flash attention + FUSED Q-PROJECTION prologue (R9-proven) -------------
__global__ __launch_bounds__(256, 2) void attn_kernel(const u16* __restrict__ xb,
                                                      const u16* __restrict__ WqT,
                                                      const u16* __restrict__ kb,
                                                      const u16* __restrict__ vT,
                                                      u16* __restrict__ attn_out) {
  __shared__ __align__(16) u16 Ks[128 * 64];       // [kv][dh], 16B groups XOR-swizzled
  __shared__ __align__(16) u16 Vs[64 * 128];       // [dh][kv], XOR-swizzled (16 groups/row)
  __shared__ __align__(16) u32 P32[4 * 4 * 16 * 20]; // [w][t][q=l15][20]: wave-private pairs
  __shared__ float Lr[4][4][16];                   // [w][t][q] partial l

  const int tid = threadIdx.x;
  const int lane = tid & 63;
  const int w = tid >> 6;
  const int l15 = lane & 15, quad = lane >> 4;
  const int bh = blockIdx.x, b = bh >> 4, h = bh & 15;
  const int q0 = blockIdx.y * 64;

  const float SC = 0.125f * 1.44269504088896340736f;   // dh^-0.5 * log2(e)
  union { u16 s[8]; bf16x8 v; } qf[4][2];

  // ---- Q-projection prologue ----
  {
    const u16* Axb = xb + (size_t)(b * NQ_ + q0) * 1024;     // 64 rows of x (bf16)
    const u16* Bwq = WqT + (size_t)(h * 64) * 1024;          // 64 Wq-columns (rows of WqT)
    const int c1 = tid, c2 = tid + 256;
    const int r1 = c1 >> 3, g1 = c1 & 7;
    const int r2 = c2 >> 3, g2 = c2 & 7;
    const size_t sO1 = (size_t)r1 * 1024 + (size_t)((g1 ^ (r1 & 7)) << 3);
    const size_t sO2 = (size_t)r2 * 1024 + (size_t)((g2 ^ (r2 & 7)) << 3);
    f32x4 qacc[4] = {};
    const int x7 = l15 & 7;
    for (int k0 = 0; k0 < 1024; k0 += 64) {
      __syncthreads();
      gload16(Axb + sO1 + k0, &Ks[w * 512]);            // A chunks [0,256)
      gload16(Axb + sO2 + k0, &Ks[2048 + w * 512]);     // A chunks [256,512)
      gload16(Bwq + sO1 + k0, &Ks[4096 + w * 512]);     // B chunks [0,256)
      gload16(Bwq + sO2 + k0, &Ks[6144 + w * 512]);     // B chunks [256,512)
      __syncthreads();
      bf16x8 af[2], bfr[4][2];
#pragma unroll
      for (int kc = 0; kc < 2; ++kc) {
        af[kc] = *(const bf16x8*)&Ks[(w * 16 + l15) * 64 + (((kc * 4 + quad) ^ x7) << 3)];
#pragma unroll
        for (int j = 0; j < 4; ++j)
          bfr[j][kc] = *(const bf16x8*)
            &Ks[4096 + (j * 16 + l15) * 64 + (((kc * 4 + quad) ^ x7) << 3)];
      }
#pragma unroll
      for (int j = 0; j < 4; ++j) {
        qacc[j] = __builtin_amdgcn_mfma_f32_16x16x32_bf16(af[0], bfr[j][0], qacc[j], 0, 0, 0);
        qacc[j] = __builtin_amdgcn_mfma_f32_16x16x32_bf16(af[1], bfr[j][1], qacc[j], 0, 0, 0);
      }
    }
    // bounce: Vs as 64x64 f32, col' = col ^ ((row&7)*8)
    float* Q64 = (float*)Vs;
#pragma unroll
    for (int j = 0; j < 4; ++j)
#pragma unroll
      for (int r = 0; r < 4; ++r) {
        int row = w * 16 + quad * 4 + r;
        Q64[row * 64 + ((j * 16 + l15) ^ ((row & 7) * 8))] = qacc[j][r];
      }
    __syncthreads();
#pragma unroll
    for (int t = 0; t < 4; ++t)
#pragma unroll
      for (int kc = 0; kc < 2; ++kc) {
        const float* qp = Q64 + (t * 16 + l15) * 64 + (((kc * 4 + quad) ^ x7) * 8);
        f32x4 lo = *(const f32x4*)qp;
        f32x4 hi = *(const f32x4*)(qp + 4);
#pragma unroll
        for (int e = 0; e < 4; ++e) {
          qf[t][kc].s[e]     = f2bf(lo[e] * SC);
          qf[t][kc].s[e + 4] = f2bf(hi[e] * SC);
        }
      }
    __syncthreads();   // all waves done reading Vs before STAGEKV overwrites it
  }

#define STAGEKV(j0) do { \
    _Pragma("unroll") \
    for (int i_ = 0; i_ < 4; ++i_) { \
      int s_ = i_ * 256 + tid; \
      int kr = s_ >> 3, kg = (s_ ^ kr) & 7; \
      gload16(kb + (size_t)(b * NKV_ + (j0) + kr) * 1024 + h * 64 + kg * 8, \
              &Ks[(i_ * 256 + w * 64) * 8]); \
      int vr = s_ >> 4, vg = (s_ ^ vr) & 15; \
      gload16(vT + (size_t)(bh * 64 + vr) * NKV_ + (j0) + vg * 8, \
              &Vs[(i_ * 256 + w * 64) * 8]); \
    } \
  } while (0)

  f32x4 Oacc[4][4] = {};
  float l_lane[4] = {0.f, 0.f, 0.f, 0.f};

  STAGEKV(0);                                // prologue: tile 0

  for (int it = 0; it < 32; ++it) {
    __syncthreads();                         // tile `it` staged (vmcnt drained per-wave)

    // fragment reads for tile `it` (this wave's complete K/V consumption)
    bf16x8 kf[2][2];
#pragma unroll
    for (int kvt = 0; kvt < 2; ++kvt)
#pragma unroll
      for (int kc = 0; kc < 2; ++kc)
        kf[kvt][kc] = *(const bf16x8*)
          &Ks[(w * 32 + kvt * 16 + l15) * 64 + (((kc * 4 + quad) ^ l15) & 7) * 8];
    bf16x8 vf[4];
#pragma unroll
    for (int d = 0; d < 4; ++d)
      vf[d] = *(const bf16x8*)
        &Vs[(d * 16 + l15) * 128 + (((w * 4 + quad) ^ l15) & 15) * 8];

    __syncthreads();                         // all waves done reading Ks/Vs

    if (it < 31) STAGEKV((it + 1) * 128);    // overwrite: overlaps full compute below

    f32x4 sacc[2][4] = {};
    __builtin_amdgcn_s_setprio(1);
#pragma unroll
    for (int kvt = 0; kvt < 2; ++kvt)
#pragma unroll
      for (int t = 0; t < 4; ++t)
#pragma unroll
        for (int kc = 0; kc < 2; ++kc)
          sacc[kvt][t] = __builtin_amdgcn_mfma_f32_16x16x32_bf16(
              kf[kvt][kc], qf[t][kc].v, sacc[kvt][t], 0, 0, 0);
    __builtin_amdgcn_s_setprio(0);

#pragma unroll
    for (int kvt = 0; kvt < 2; ++kvt)
#pragma unroll
      for (int t = 0; t < 4; ++t) {
        float p0 = __builtin_amdgcn_exp2f(sacc[kvt][t][0]);
        float p1 = __builtin_amdgcn_exp2f(sacc[kvt][t][1]);
        float p2 = __builtin_amdgcn_exp2f(sacc[kvt][t][2]);
        float p3 = __builtin_amdgcn_exp2f(sacc[kvt][t][3]);
        l_lane[t] += (p0 + p1) + (p2 + p3);
        uint2 pk; pk.x = pack2rn(p0, p1); pk.y = pack2rn(p2, p3);
        *(uint2*)&P32[((w * 4 + t) * 16 + l15) * 20 + kvt * 8 + quad * 2] = pk;
      }

    bf16x8 pf[4];
#pragma unroll
    for (int t = 0; t < 4; ++t)
      pf[t] = *(const bf16x8*)&P32[((w * 4 + t) * 16 + l15) * 20 + quad * 4];
    __builtin_amdgcn_s_setprio(1);
#pragma unroll
    for (int d = 0; d < 4; ++d)
#pragma unroll
      for (int t = 0; t < 4; ++t)
        Oacc[d][t] = __builtin_amdgcn_mfma_f32_16x16x32_bf16(vf[d], pf[t], Oacc[d][t],
                                                             0, 0, 0);
    __builtin_amdgcn_s_setprio(0);
  }
#undef STAGEKV

#pragma unroll
  for (int t = 0; t < 4; ++t) {
    l_lane[t] += __shfl_xor(l_lane[t], 16);
    l_lane[t] += __shfl_xor(l_lane[t], 32);
  }
  if (quad == 0) {
#pragma unroll
    for (int t = 0; t < 4; ++t) Lr[w][t][l15] = l_lane[t];
  }
  __syncthreads();
  float inv = 1.0f / (Lr[0][w][l15] + Lr[1][w][l15] + Lr[2][w][l15] + Lr[3][w][l15]);

  float* red = (float*)P32;
  u16* ob = attn_out + (size_t)(b * NQ_ + q0 + w * 16 + l15) * INNER_ + h * 64;
#pragma unroll
  for (int d = 0; d < 4; ++d) {
    __syncthreads();
#pragma unroll
    for (int t = 0; t < 4; ++t)
      *(f32x4*)&red[(w * 4 + t) * 256 + quad * 64 + l15 * 4] = Oacc[d][t];
    __syncthreads();
    f32x4 r = *(const f32x4*)&red[(0 * 4 + w) * 256 + quad * 64 + l15 * 4];
#pragma unroll
    for (int ww = 1; ww < 4; ++ww) {
      f32x4 c = *(const f32x4*)&red[(ww * 4 + w) * 256 + quad * 64 + l15 * 4];
      r[0] += c[0]; r[1] += c[1]; r[2] += c[2]; r[3] += c[3];
    }
    *(u32*)(ob + d * 16 + quad * 4)     = pack2(r[0] * inv, r[1] * inv);
    *(u32*)(ob + d * 16 + quad * 4 + 2) = pack2(r[2] * inv, r[3] * inv);
  }
}

// ---------------- driver ----------------
extern "C" void kernel_launch(void* const* d_in, const int* in_sizes, int n_in,
                              void* d_out, int out_size, void* d_ws, size_t ws_size,
                              hipStream_t stream) {
  const float* x    = (const float*)d_in[0];
  const float* ctx  = (const float*)d_in[1];
  const float* Wq   = (const float*)d_in[2];
  const float* Wkv  = (const float*)d_in[3];
  const float* Wout = (const float*)d_in[4];
  const float* bout = (const float*)d_in[5];

  char* ws = (char*)d_ws;
  u16* xb    = (u16*)(ws + (size_t)( 0u << 20));  // 4 MB  [live through attn prologue]
  u16* ctxb  = (u16*)(ws + (size_t)( 4u << 20));  // 16 MB [dead after kv_gemm]
  u16* WqT   = (u16*)(ws + (size_t)(20u << 20));  // 2 MB  [live through attn prologue]
  u16* WkvT  = (u16*)(ws + (size_t)(22u << 20));  // 4 MB
  u16* WoutT = (u16*)(ws + (size_t)(26u << 20));  // 2 MB
  u16* ab    = (u16*)(ws + (size_t)(28u << 20));  // 4 MB  [old qb slot; NOT aliasing xb]
  u16* kb    = (u16*)(ws + (size_t)(32u << 20));  // 16 MB (K row-major bf16)
  u16* vTb   = (u16*)(ws + (size_t)(48u << 20));  // 16 MB (V transposed [bh*64+dh][NKV])

  // casts + weight transposes in one dispatch (64x64 transpose tiles, fat casts)
  prep<<<1664, 256, 0, stream>>>(x, ctx, Wq, Wkv, Wout, xb, ctxb, WqT, WkvT, WoutT);
  // kv projection: 256 blocks of 256x256, faithful 8-phase, 1 block/CU
  kv_gemm<<<256, 512, 0, stream>>>(ctxb, WkvT, kb, vTb);
  // fused q-projection + softmax attention: 512 blocks x 256 threads
  attn_kernel<<<dim3(32, 16), 256, 0, stream>>>(xb, WqT, kb, vTb, ab);
  // out = attn Wout + b_out : fp32, 256 blocks, tri-buffered pipeline
  out_gemm<<<256, 256, 0, stream>>>(ab, WoutT, (float*)d_out, bout);
}

// Round 12
// 206.458 us; speedup vs baseline: 1.0129x; 1.0129x over previous
//
#include <hip/hip_runtime.h>
#include <stdint.h>

// Problem constants
#define B_    2
#define NQ_   1024
#define NKV_  4096
#define DQ_   1024
#define H_    16
#define DH_   64
#define INNER_ 1024

typedef unsigned short u16;
typedef uint32_t u32;
typedef __bf16 bf16x8 __attribute__((ext_vector_type(8)));
typedef float  f32x4  __attribute__((ext_vector_type(4)));

__device__ __forceinline__ u16 f2bf(float x) {           // RNE
  union { float f; uint32_t u; } v; v.f = x;
  uint32_t r = v.u + 0x7FFFu + ((v.u >> 16) & 1u);
  return (u16)(r >> 16);
}
__device__ __forceinline__ u32 pack2(float a, float b) { // RNE pair
  return (u32)f2bf(a) | ((u32)f2bf(b) << 16);
}
__device__ __forceinline__ u32 cvtpk(float lo, float hi) { // 1-VALU packed cvt (RNE)
  u32 r;
  asm("v_cvt_pk_bf16_f32 %0, %1, %2" : "=v"(r) : "v"(lo), "v"(hi));
  return r;
}
__device__ __forceinline__ float bf2f(u16 s) {
  union { float f; uint32_t u; } v; v.u = ((uint32_t)s) << 16; return v.f;
}

// async global->LDS, 16B/lane; lds base wave-uniform, hw adds lane*16
__device__ __forceinline__ void gload16(const void* g, void* l) {
  __builtin_amdgcn_global_load_lds((const __attribute__((address_space(1))) void*)g,
                                   (__attribute__((address_space(3))) void*)l,
                                   16, 0, 0);
}

// ---------------- fused prep: casts + weight transposes in ONE dispatch -----------------
// blocks [0,640): fat casts (16 x float4 per thread; x=128 blocks, ctx=512);
// [640,896): Wq^T 64x64 tiles; [896,1408): Wkv^T; [1408,1664): Wout^T.
__global__ __launch_bounds__(256) void prep(const float* __restrict__ x,
                                            const float* __restrict__ ctx,
                                            const float* __restrict__ Wq,
                                            const float* __restrict__ Wkv,
                                            const float* __restrict__ Wout,
                                            u16* __restrict__ xb,
                                            u16* __restrict__ ctxb,
                                            u16* __restrict__ WqT,
                                            u16* __restrict__ WkvT,
                                            u16* __restrict__ WoutT) {
  int bid = blockIdx.x;
  if (bid < 640) {                         // elementwise cast, 64 elems/thread
    const float* src; u16* dst; int fbase;  // float4 units
    if (bid < 128) { src = x;   dst = xb;   fbase = bid * 4096; }
    else           { src = ctx; dst = ctxb; fbase = (bid - 128) * 4096; }
#pragma unroll
    for (int u = 0; u < 16; ++u) {
      int i = (fbase + u * 256 + threadIdx.x) * 4;
      float4 v = *(const float4*)(src + i);
      uint2 o; o.x = pack2(v.x, v.y); o.y = pack2(v.z, v.w);
      *(uint2*)(dst + i) = o;
    }
    return;
  }
  // transpose+cast W[K][N] -> Wt[N][K], 64x64 tiles
  __shared__ float tile[64][65];           // 16.6 KB
  const float* W; u16* Wt; int K, N, local, ntm;  // ntm = n-tiles mask
  int b2 = bid - 640;
  if (b2 < 256)      { W = Wq;   Wt = WqT;   K = 1024; N = 1024; local = b2;       ntm = 15; }
  else if (b2 < 768) { W = Wkv;  Wt = WkvT;  K = 1024; N = 2048; local = b2 - 256; ntm = 31; }
  else               { W = Wout; Wt = WoutT; K = 1024; N = 1024; local = b2 - 768; ntm = 15; }
  int n0 = (local & ntm) * 64;
  int k0 = (ntm == 15) ? (local >> 4) * 64 : (local >> 5) * 64;
  int tx = threadIdx.x & 63, ty = threadIdx.x >> 6;    // 64 x 4
  for (int i = ty; i < 64; i += 4)
    tile[i][tx] = W[(size_t)(k0 + i) * N + n0 + tx];
  __syncthreads();
  // packed u32 stores: 32 k-pairs x 8 rows per pass -> two 128B runs per wave
  int tx2 = threadIdx.x & 31, ty2 = threadIdx.x >> 5;  // 32 x 8
  for (int j = ty2; j < 64; j += 8)
    *(u32*)&Wt[(size_t)(n0 + j) * K + k0 + tx2 * 2] =
        pack2(tile[tx2 * 2][j], tile[tx2 * 2 + 1][j]);
}

// ---------------- kv projection: 256x256 / BK=64 / FAITHFUL 8-phase schedule ------------
// R8-proven. 2 K-steps per iteration; counted vmcnt(6) only at ph4/ph8; stage ledger
// WAR-safe; every wait's targets >=4 phases old. Epilogues round-1 proven.
__global__ __launch_bounds__(512, 2) void kv_gemm(const u16* __restrict__ ctxb,
                                                  const u16* __restrict__ WkvT,
                                                  u16* __restrict__ kb,
                                                  u16* __restrict__ vTb) {
  __shared__ __align__(16) u16 As[2][256 * 64];   // 64 KiB
  __shared__ __align__(16) u16 Bs[2][256 * 64];   // 64 KiB
  const int tid = threadIdx.x;
  const int lane = tid & 63;
  const int w = tid >> 6;                 // 0..7
  const int wr = w >> 2, wc = w & 3;      // 2 x 4 waves -> wave panel 128M x 64N
  const int l15 = lane & 15, quad = lane >> 4;
  const int K = 1024;

  // XCD-chunked bijective swizzle
  int bid = blockIdx.x;
  int wgid = (bid & 7) * 32 + (bid >> 3);
  const int tm = wgid >> 3, tn = wgid & 7;
  const int m0 = tm * 256, n0 = tn * 256;
  const u16* Ag = ctxb + (size_t)m0 * K;
  const u16* Bg = WkvT + (size_t)n0 * K;

  // per-thread stage source offsets (u16 units): row-reorder + chunk XOR pre-swizzle
  size_t offA[2][2], offB[2][2];
#pragma unroll
  for (int ah = 0; ah < 2; ++ah)
#pragma unroll
    for (int p = 0; p < 2; ++p) {
      int c = p * 512 + (w << 6) + lane;  // chunk id within 16 KiB region
      int s = ah * 128 + (c >> 3);        // LDS slot (reordered row)
      int col = ((c & 7) ^ (s & 7)) << 3; // pre-swizzled source column (bf16)
      int rA = ((s >> 6) & 1) * 128 + ((s >> 7) & 1) * 64 + (s & 63);
      int rB = ((s >> 5) & 3) * 64 + ((s >> 7) & 1) * 32 + (s & 31);
      offA[ah][p] = (size_t)rA * 1024 + col;
      offB[ah][p] = (size_t)rB * 1024 + col;
    }

#define STAGE_A(bufi, ah, kk) do { \
    gload16(Ag + offA[ah][0] + (kk), &As[bufi][(ah) * 8192 + (w << 9)]); \
    gload16(Ag + offA[ah][1] + (kk), &As[bufi][(ah) * 8192 + 4096 + (w << 9)]); \
  } while (0)
#define STAGE_B(bufi, bh, kk) do { \
    gload16(Bg + offB[bh][0] + (kk), &Bs[bufi][(bh) * 8192 + (w << 9)]); \
    gload16(Bg + offB[bh][1] + (kk), &Bs[bufi][(bh) * 8192 + 4096 + (w << 9)]); \
  } while (0)
#define LDA2(dst, i8, bufi) do { \
    const int _s = ((i8) >> 2) * 128 + wr * 64 + ((i8) & 3) * 16 + l15; \
    const u16* _p = &As[bufi][_s * 64]; const int _x = _s & 7; \
    dst[0] = *(const bf16x8*)&_p[(quad ^ _x) << 3]; \
    dst[1] = *(const bf16x8*)&_p[((quad + 4) ^ _x) << 3]; \
  } while (0)
#define LDB2(dst, j, bufi) do { \
    const int _s = ((j) >> 1) * 128 + wc * 32 + ((j) & 1) * 16 + l15; \
    const u16* _p = &Bs[bufi][_s * 64]; const int _x = _s & 7; \
    dst[0] = *(const bf16x8*)&_p[(quad ^ _x) << 3]; \
    dst[1] = *(const bf16x8*)&_p[((quad + 4) ^ _x) << 3]; \
  } while (0)
#define MF(i0, j0, bb) do { \
    _Pragma("unroll") \
    for (int _i = 0; _i < 4; ++_i) { \
      acc[(i0) + _i][(j0)    ] = __builtin_amdgcn_mfma_f32_16x16x32_bf16(a[_i][0], bb[0][0], acc[(i0) + _i][(j0)    ], 0, 0, 0); \
      acc[(i0) + _i][(j0)    ] = __builtin_amdgcn_mfma_f32_16x16x32_bf16(a[_i][1], bb[0][1], acc[(i0) + _i][(j0)    ], 0, 0, 0); \
      acc[(i0) + _i][(j0) + 1] = __builtin_amdgcn_mfma_f32_16x16x32_bf16(a[_i][0], bb[1][0], acc[(i0) + _i][(j0) + 1], 0, 0, 0); \
      acc[(i0) + _i][(j0) + 1] = __builtin_amdgcn_mfma_f32_16x16x32_bf16(a[_i][1], bb[1][1], acc[(i0) + _i][(j0) + 1], 0, 0, 0); \
    } \
  } while (0)
#define BAR()   __builtin_amdgcn_s_barrier()
#define LGKM0() asm volatile("s_waitcnt lgkmcnt(0)" ::: "memory")

  f32x4 acc[8][4] = {};
  bf16x8 a[4][2], b[2][2], c2[2][2];

  // prologue: step0 full (Aa,Ba,Bb,Ab) + step1 trio (Aa,Ba,Bb) = 14 loads
  STAGE_A(0, 0, 0);
  STAGE_B(0, 0, 0);
  STAGE_B(0, 1, 0);
  STAGE_A(0, 1, 0);
  STAGE_A(1, 0, 64);
  STAGE_B(1, 0, 64);
  STAGE_B(1, 1, 64);
  asm volatile("s_waitcnt vmcnt(6)" ::: "memory");   // step0's 8 loads complete
  BAR();

#define HALF(bufi, kAb, kNext, STG, WMID, WEND) do { \
    LDB2(b[0], 0, bufi); LDB2(b[1], 1, bufi); \
    LDA2(a[0], 0, bufi); LDA2(a[1], 1, bufi); LDA2(a[2], 2, bufi); LDA2(a[3], 3, bufi); \
    if (kAb >= 0) STAGE_A((bufi) ^ 1, 1, kAb); \
    BAR(); LGKM0(); \
    __builtin_amdgcn_s_setprio(1); MF(0, 0, b); __builtin_amdgcn_s_setprio(0); \
    BAR(); \
    LDB2(c2[0], 2, bufi); LDB2(c2[1], 3, bufi); \
    if (STG) STAGE_A(bufi, 0, kNext); \
    BAR(); LGKM0(); \
    __builtin_amdgcn_s_setprio(1); MF(0, 2, c2); __builtin_amdgcn_s_setprio(0); \
    BAR(); \
    LDA2(a[0], 4, bufi); LDA2(a[1], 5, bufi); LDA2(a[2], 6, bufi); LDA2(a[3], 7, bufi); \
    if (STG) STAGE_B(bufi, 0, kNext); \
    BAR(); LGKM0(); \
    __builtin_amdgcn_s_setprio(1); MF(4, 0, b); __builtin_amdgcn_s_setprio(0); \
    BAR(); \
    if (STG) STAGE_B(bufi, 1, kNext); \
    BAR(); \
    __builtin_amdgcn_s_setprio(1); MF(4, 2, c2); __builtin_amdgcn_s_setprio(0); \
    WMID; \
    BAR(); \
  } while (0)

  for (int i = 0; i < 7; ++i) {
    const int k2 = i * 128;
    HALF(0, k2 + 64, k2 + 128, 1,
         asm volatile("s_waitcnt vmcnt(6)" ::: "memory"), );
    HALF(1, k2 + 128, k2 + 192, 1,
         asm volatile("s_waitcnt vmcnt(6)" ::: "memory"), );
  }
  HALF(0, 960, 0, 0,
       asm volatile("s_waitcnt vmcnt(0)" ::: "memory"), );
  HALF(1, -1, 0, 0, , );

#undef HALF
#undef BAR
#undef LGKM0

  // epilogue (round-1 proven): tn<4 -> K row-major, tn>=4 -> V transposed scatter
  if (tn < 4) {
#pragma unroll
    for (int i8 = 0; i8 < 8; ++i8)
#pragma unroll
      for (int j = 0; j < 4; ++j) {
        int col = n0 + wc * 64 + j * 16 + l15;
#pragma unroll
        for (int r = 0; r < 4; ++r) {
          int row = m0 + wr * 128 + i8 * 16 + quad * 4 + r;
          kb[(size_t)row * 1024 + col] = f2bf(acc[i8][j][r]);
        }
      }
  } else {
    const int bb_ = m0 >> 12;
#pragma unroll
    for (int i8 = 0; i8 < 8; ++i8) {
      int kvr = (m0 & 4095) + wr * 128 + i8 * 16 + quad * 4;
#pragma unroll
      for (int j = 0; j < 4; ++j) {
        int c = (n0 - 1024) + wc * 64 + j * 16 + l15;
        int h = c >> 6, dh = c & 63;
        uint2 st;
        st.x = pack2(acc[i8][j][0], acc[i8][j][1]);
        st.y = pack2(acc[i8][j][2], acc[i8][j][3]);
        *(uint2*)&vTb[((size_t)((bb_ * 16 + h) * 64 + dh)) * NKV_ + kvr] = st;
      }
    }
  }
#undef STAGE_A
#undef STAGE_B
#undef LDA2
#undef LDB2
#undef MF
}

// ---------------- out-proj GEMM: 64x128 tiles, tri-buffered counted-vmcnt pipeline ------
__global__ __launch_bounds__(256) void out_gemm(const u16* __restrict__ A,
                                                const u16* __restrict__ Bt,
                                                float* __restrict__ Cout,
                                                const float* __restrict__ bias) {
  __shared__ __align__(16) u16 As[3][64 * 32];    // 12 KB
  __shared__ __align__(16) u16 Bs[3][128 * 32];   // 24 KB
  const int tid = threadIdx.x;
  const int lane = tid & 63;
  const int w = tid >> 6;
  const int wr = w >> 1, wc = w & 1;           // wave covers 32M x 64N
  const int l15 = lane & 15, quad = lane >> 4;
  const int unit = blockIdx.x;
  const int m0 = (unit >> 3) * 64, n0 = (unit & 7) * 128;
  const int K = 1024, N = 1024;

  const u16* Ab = A + (size_t)m0 * K;
  const u16* Bb = Bt + (size_t)n0 * K;
  f32x4 acc[2][4] = {};

  const int ar = tid >> 2, ac = (tid & 3) << 3;          // A: 256 chunks, 1/thread
  const int q1 = w * 64 + lane, q2 = q1 + 256;           // B: 512 chunks, 2/thread
  const int br1 = q1 >> 2, bc1 = (q1 & 3) << 3;
  const int br2 = q2 >> 2, bc2 = (q2 & 3) << 3;

#define STG(bi, k0) do { \
    gload16(Ab + (size_t)ar * K + (k0) + ac, &As[bi][w * 512]); \
    gload16(Bb + (size_t)br1 * K + (k0) + bc1, &Bs[bi][w * 512]); \
    gload16(Bb + (size_t)br2 * K + (k0) + bc2, &Bs[bi][2048 + w * 512]); \
  } while (0)

  STG(0, 0);
  STG(1, 32);
  asm volatile("s_waitcnt vmcnt(3)" ::: "memory");   // STG(0) complete, STG(1) in flight
  __builtin_amdgcn_s_barrier();

  for (int it = 0; it < 32; ++it) {
    const int cur = it % 3;
    bf16x8 af[2], bfr[4];
#pragma unroll
    for (int i = 0; i < 2; ++i)
      af[i] = *(const bf16x8*)&As[cur][(wr * 32 + i * 16 + l15) * 32 + quad * 8];
#pragma unroll
    for (int j = 0; j < 4; ++j)
      bfr[j] = *(const bf16x8*)&Bs[cur][(wc * 64 + j * 16 + l15) * 32 + quad * 8];
    if (it + 2 < 32) STG((it + 2) % 3, (it + 2) * 32);
    __builtin_amdgcn_s_barrier();
    asm volatile("s_waitcnt lgkmcnt(0)" ::: "memory");
    __builtin_amdgcn_s_setprio(1);
#pragma unroll
    for (int i = 0; i < 2; ++i)
#pragma unroll
      for (int j = 0; j < 4; ++j)
        acc[i][j] = __builtin_amdgcn_mfma_f32_16x16x32_bf16(af[i], bfr[j], acc[i][j], 0, 0, 0);
    __builtin_amdgcn_s_setprio(0);
    if (it + 2 < 32)      { asm volatile("s_waitcnt vmcnt(3)" ::: "memory"); }
    else if (it + 2 == 32){ asm volatile("s_waitcnt vmcnt(0)" ::: "memory"); }
    __builtin_amdgcn_s_barrier();
  }
#undef STG

#pragma unroll
  for (int i = 0; i < 2; ++i)
#pragma unroll
    for (int j = 0; j < 4; ++j) {
      int col = n0 + wc * 64 + j * 16 + l15;
      float bv = bias[col];
#pragma unroll
      for (int r = 0; r < 4; ++r) {
        int row = m0 + wr * 32 + i * 16 + quad * 4 + r;
        Cout[(size_t)row * N + col] = acc[i][j][r] + bv;
      }
    }
}

// ---------------- flash attention + fused Q-projection (dbuf prologue, cvt_pk) ----------
// R9-proven structure. Prologue mini-GEMM now double-buffered (Ks<->Vs as 16KB A|B
// buffers; counted vmcnt(4); lgkm0-before-barrier protects reads from overwrite);
// f32 Q bounce moved to P32. Softmax pack uses v_cvt_pk_bf16_f32 (1 VALU vs 3).
__global__ __launch_bounds__(256, 2) void attn_kernel(const u16* __restrict__ xb,
                                                      const u16* __restrict__ WqT,
                                                      const u16* __restrict__ kb,
                                                      const u16* __restrict__ vT,
                                                      u16* __restrict__ attn_out) {
  __shared__ __align__(16) u16 Ks[128 * 64];       // [kv][dh], 16B groups XOR-swizzled
  __shared__ __align__(16) u16 Vs[64 * 128];       // [dh][kv], XOR-swizzled (16 groups/row)
  __shared__ __align__(16) u32 P32[4 * 4 * 16 * 20]; // [w][t][q=l15][20]: wave-private pairs
  __shared__ float Lr[4][4][16];                   // [w][t][q] partial l

  const int tid = threadIdx.x;
  const int lane = tid & 63;
  const int w = tid >> 6;
  const int l15 = lane & 15, quad = lane >> 4;
  const int bh = blockIdx.x, b = bh >> 4, h = bh & 15;
  const int q0 = blockIdx.y * 64;

  const float SC = 0.125f * 1.44269504088896340736f;   // dh^-0.5 * log2(e)
  union { u16 s[8]; bf16x8 v; } qf[4][2];

  // ---- Q-projection prologue (double-buffered) ----
  {
    const u16* Axb = xb + (size_t)(b * NQ_ + q0) * 1024;     // 64 rows of x (bf16)
    const u16* Bwq = WqT + (size_t)(h * 64) * 1024;          // 64 Wq-columns
    const int c1 = tid, c2 = tid + 256;
    const int r1 = c1 >> 3, g1 = c1 & 7;
    const int r2 = c2 >> 3, g2 = c2 & 7;
    const size_t sO1 = (size_t)r1 * 1024 + (size_t)((g1 ^ (r1 & 7)) << 3);
    const size_t sO2 = (size_t)r2 * 1024 + (size_t)((g2 ^ (r2 & 7)) << 3);
    f32x4 qacc[4] = {};
    const int x7 = l15 & 7;

#define QSTG(dst, kk) do { \
      gload16(Axb + sO1 + (kk), &dst[w * 512]); \
      gload16(Axb + sO2 + (kk), &dst[2048 + w * 512]); \
      gload16(Bwq + sO1 + (kk), &dst[4096 + w * 512]); \
      gload16(Bwq + sO2 + (kk), &dst[6144 + w * 512]); \
    } while (0)

#define QSTEP(dst, kk, DOSTG, W4, W0) do { \
      bf16x8 af_[2], bfr_[4][2]; \
      _Pragma("unroll") \
      for (int kc = 0; kc < 2; ++kc) { \
        af_[kc] = *(const bf16x8*)&dst[(w * 16 + l15) * 64 + (((kc * 4 + quad) ^ x7) << 3)]; \
        _Pragma("unroll") \
        for (int j = 0; j < 4; ++j) \
          bfr_[j][kc] = *(const bf16x8*) \
            &dst[4096 + (j * 16 + l15) * 64 + (((kc * 4 + quad) ^ x7) << 3)]; \
      } \
      asm volatile("s_waitcnt lgkmcnt(0)" ::: "memory"); \
      __builtin_amdgcn_s_barrier(); \
      if (DOSTG) QSTG(dst, kk); \
      _Pragma("unroll") \
      for (int j = 0; j < 4; ++j) { \
        qacc[j] = __builtin_amdgcn_mfma_f32_16x16x32_bf16(af_[0], bfr_[j][0], qacc[j], 0, 0, 0); \
        qacc[j] = __builtin_amdgcn_mfma_f32_16x16x32_bf16(af_[1], bfr_[j][1], qacc[j], 0, 0, 0); \
      } \
      if (W4)      { asm volatile("s_waitcnt vmcnt(4)" ::: "memory"); } \
      else if (W0) { asm volatile("s_waitcnt vmcnt(0)" ::: "memory"); } \
      __builtin_amdgcn_s_barrier(); \
    } while (0)

    QSTG(Ks, 0);
    QSTG(Vs, 64);
    asm volatile("s_waitcnt vmcnt(4)" ::: "memory");   // Ks's 4 complete, Vs in flight
    __builtin_amdgcn_s_barrier();
#pragma unroll
    for (int i = 0; i < 16; i += 2) {
      QSTEP(Ks, (i + 2) * 64, (i + 2) < 16, (i + 2) < 16, (i + 2) == 16);
      QSTEP(Vs, (i + 3) * 64, (i + 3) < 16, (i + 3) < 16, 0);
    }
#undef QSTG
#undef QSTEP

    // bounce: P32 as 64x64 f32, col' = col ^ ((row&7)*8)
    float* Q64 = (float*)P32;
#pragma unroll
    for (int j = 0; j < 4; ++j)
#pragma unroll
      for (int r = 0; r < 4; ++r) {
        int row = w * 16 + quad * 4 + r;
        Q64[row * 64 + ((j * 16 + l15) ^ ((row & 7) * 8))] = qacc[j][r];
      }
    __syncthreads();
#pragma unroll
    for (int t = 0; t < 4; ++t)
#pragma unroll
      for (int kc = 0; kc < 2; ++kc) {
        const float* qp = Q64 + (t * 16 + l15) * 64 + (((kc * 4 + quad) ^ x7) * 8);
        f32x4 lo = *(const f32x4*)qp;
        f32x4 hi = *(const f32x4*)(qp + 4);
#pragma unroll
        for (int e = 0; e < 4; ++e) {
          qf[t][kc].s[e]     = f2bf(lo[e] * SC);
          qf[t][kc].s[e + 4] = f2bf(hi[e] * SC);
        }
      }
    __syncthreads();   // all qf reads done before main loop reuses P32
  }

#define STAGEKV(j0) do { \
    _Pragma("unroll") \
    for (int i_ = 0; i_ < 4; ++i_) { \
      int s_ = i_ * 256 + tid; \
      int kr = s_ >> 3, kg = (s_ ^ kr) & 7; \
      gload16(kb + (size_t)(b * NKV_ + (j0) + kr) * 1024 + h * 64 + kg * 8, \
              &Ks[(i_ * 256 + w * 64) * 8]); \
      int vr = s_ >> 4, vg = (s_ ^ vr) & 15; \
      gload16(vT + (size_t)(bh * 64 + vr) * NKV_ + (j0) + vg * 8, \
              &Vs[(i_ * 256 + w * 64) * 8]); \
    } \
  } while (0)

  f32x4 Oacc[4][4] = {};
  float l_lane[4] = {0.f, 0.f, 0.f, 0.f};

  STAGEKV(0);                                // prologue: tile 0

  for (int it = 0; it < 32; ++it) {
    __syncthreads();                         // tile `it` staged (vmcnt drained per-wave)

    // fragment reads for tile `it` (this wave's complete K/V consumption)
    bf16x8 kf[2][2];
#pragma unroll
    for (int kvt = 0; kvt < 2; ++kvt)
#pragma unroll
      for (int kc = 0; kc < 2; ++kc)
        kf[kvt][kc] = *(const bf16x8*)
          &Ks[(w * 32 + kvt * 16 + l15) * 64 + (((kc * 4 + quad) ^ l15) & 7) * 8];
    bf16x8 vf[4];
#pragma unroll
    for (int d = 0; d < 4; ++d)
      vf[d] = *(const bf16x8*)
        &Vs[(d * 16 + l15) * 128 + (((w * 4 + quad) ^ l15) & 15) * 8];

    __syncthreads();                         // all waves done reading Ks/Vs

    if (it < 31) STAGEKV((it + 1) * 128);    // overwrite: overlaps full compute below

    f32x4 sacc[2][4] = {};
    __builtin_amdgcn_s_setprio(1);
#pragma unroll
    for (int kvt = 0; kvt < 2; ++kvt)
#pragma unroll
      for (int t = 0; t < 4; ++t)
#pragma unroll
        for (int kc = 0; kc < 2; ++kc)
          sacc[kvt][t] = __builtin_amdgcn_mfma_f32_16x16x32_bf16(
              kf[kvt][kc], qf[t][kc].v, sacc[kvt][t], 0, 0, 0);
    __builtin_amdgcn_s_setprio(0);

#pragma unroll
    for (int kvt = 0; kvt < 2; ++kvt)
#pragma unroll
      for (int t = 0; t < 4; ++t) {
        float p0 = __builtin_amdgcn_exp2f(sacc[kvt][t][0]);
        float p1 = __builtin_amdgcn_exp2f(sacc[kvt][t][1]);
        float p2 = __builtin_amdgcn_exp2f(sacc[kvt][t][2]);
        float p3 = __builtin_amdgcn_exp2f(sacc[kvt][t][3]);
        l_lane[t] += (p0 + p1) + (p2 + p3);
        uint2 pk; pk.x = cvtpk(p0, p1); pk.y = cvtpk(p2, p3);
        *(uint2*)&P32[((w * 4 + t) * 16 + l15) * 20 + kvt * 8 + quad * 2] = pk;
      }

    bf16x8 pf[4];
#pragma unroll
    for (int t = 0; t < 4; ++t)
      pf[t] = *(const bf16x8*)&P32[((w * 4 + t) * 16 + l15) * 20 + quad * 4];
    __builtin_amdgcn_s_setprio(1);
#pragma unroll
    for (int d = 0; d < 4; ++d)
#pragma unroll
      for (int t = 0; t < 4; ++t)
        Oacc[d][t] = __builtin_amdgcn_mfma_f32_16x16x32_bf16(vf[d], pf[t], Oacc[d][t],
                                                             0, 0, 0);
    __builtin_amdgcn_s_setprio(0);
  }
#undef STAGEKV

#pragma unroll
  for (int t = 0; t < 4; ++t) {
    l_lane[t] += __shfl_xor(l_lane[t], 16);
    l_lane[t] += __shfl_xor(l_lane[t], 32);
  }
  if (quad == 0) {
#pragma unroll
    for (int t = 0; t < 4; ++t) Lr[w][t][l15] = l_lane[t];
  }
  __syncthreads();
  float inv = 1.0f / (Lr[0][w][l15] + Lr[1][w][l15] + Lr[2][w][l15] + Lr[3][w][l15]);

  float* red = (float*)P32;
  u16* ob = attn_out + (size_t)(b * NQ_ + q0 + w * 16 + l15) * INNER_ + h * 64;
#pragma unroll
  for (int d = 0; d < 4; ++d) {
    __syncthreads();
#pragma unroll
    for (int t = 0; t < 4; ++t)
      *(f32x4*)&red[(w * 4 + t) * 256 + quad * 64 + l15 * 4] = Oacc[d][t];
    __syncthreads();
    f32x4 r = *(const f32x4*)&red[(0 * 4 + w) * 256 + quad * 64 + l15 * 4];
#pragma unroll
    for (int ww = 1; ww < 4; ++ww) {
      f32x4 c = *(const f32x4*)&red[(ww * 4 + w) * 256 + quad * 64 + l15 * 4];
      r[0] += c[0]; r[1] += c[1]; r[2] += c[2]; r[3] += c[3];
    }
    *(u32*)(ob + d * 16 + quad * 4)     = pack2(r[0] * inv, r[1] * inv);
    *(u32*)(ob + d * 16 + quad * 4 + 2) = pack2(r[2] * inv, r[3] * inv);
  }
}

// ---------------- driver ----------------
extern "C" void kernel_launch(void* const* d_in, const int* in_sizes, int n_in,
                              void* d_out, int out_size, void* d_ws, size_t ws_size,
                              hipStream_t stream) {
  const float* x    = (const float*)d_in[0];
  const float* ctx  = (const float*)d_in[1];
  const float* Wq   = (const float*)d_in[2];
  const float* Wkv  = (const float*)d_in[3];
  const float* Wout = (const float*)d_in[4];
  const float* bout = (const float*)d_in[5];

  char* ws = (char*)d_ws;
  u16* xb    = (u16*)(ws + (size_t)( 0u << 20));  // 4 MB  [live through attn prologue]
  u16* ctxb  = (u16*)(ws + (size_t)( 4u << 20));  // 16 MB [dead after kv_gemm]
  u16* WqT   = (u16*)(ws + (size_t)(20u << 20));  // 2 MB  [live through attn prologue]
  u16* WkvT  = (u16*)(ws + (size_t)(22u << 20));  // 4 MB
  u16* WoutT = (u16*)(ws + (size_t)(26u << 20));  // 2 MB
  u16* ab    = (u16*)(ws + (size_t)(28u << 20));  // 4 MB  [old qb slot; NOT aliasing xb]
  u16* kb    = (u16*)(ws + (size_t)(32u << 20));  // 16 MB (K row-major bf16)
  u16* vTb   = (u16*)(ws + (size_t)(48u << 20));  // 16 MB (V transposed [bh*64+dh][NKV])

  // casts + weight transposes in one dispatch (64x64 transpose tiles, fat casts)
  prep<<<1664, 256, 0, stream>>>(x, ctx, Wq, Wkv, Wout, xb, ctxb, WqT, WkvT, WoutT);
  // kv projection: 256 blocks of 256x256, faithful 8-phase, 1 block/CU
  kv_gemm<<<256, 512, 0, stream>>>(ctxb, WkvT, kb, vTb);
  // fused q-projection + softmax attention: 512 blocks x 256 threads
  attn_kernel<<<dim3(32, 16), 256, 0, stream>>>(xb, WqT, kb, vTb, ab);
  // out = attn Wout + b_out : fp32, 256 blocks, tri-buffered pipeline
  out_gemm<<<256, 256, 0, stream>>>(ab, WoutT, (float*)d_out, bout);
}

// Round 13
// 205.162 us; speedup vs baseline: 1.0193x; 1.0063x over previous
//
#include <hip/hip_runtime.h>
#include <stdint.h>

// Problem constants
#define B_    2
#define NQ_   1024
#define NKV_  4096
#define DQ_   1024
#define H_    16
#define DH_   64
#define INNER_ 1024

typedef unsigned short u16;
typedef uint32_t u32;
typedef __bf16 bf16x8 __attribute__((ext_vector_type(8)));
typedef float  f32x4  __attribute__((ext_vector_type(4)));

__device__ __forceinline__ u16 f2bf(float x) {           // RNE
  union { float f; uint32_t u; } v; v.f = x;
  uint32_t r = v.u + 0x7FFFu + ((v.u >> 16) & 1u);
  return (u16)(r >> 16);
}
__device__ __forceinline__ u32 pack2(float a, float b) { // RNE pair
  return (u32)f2bf(a) | ((u32)f2bf(b) << 16);
}
__device__ __forceinline__ u32 cvtpk(float lo, float hi) { // 1-VALU packed cvt (RNE)
  u32 r;
  asm("v_cvt_pk_bf16_f32 %0, %1, %2" : "=v"(r) : "v"(lo), "v"(hi));
  return r;
}
__device__ __forceinline__ float bf2f(u16 s) {
  union { float f; uint32_t u; } v; v.u = ((uint32_t)s) << 16; return v.f;
}

// async global->LDS, 16B/lane; lds base wave-uniform, hw adds lane*16
__device__ __forceinline__ void gload16(const void* g, void* l) {
  __builtin_amdgcn_global_load_lds((const __attribute__((address_space(1))) void*)g,
                                   (__attribute__((address_space(3))) void*)l,
                                   16, 0, 0);
}

// ---------------- fused prep: casts + weight transposes in ONE dispatch -----------------
// blocks [0,640): fat casts (16 x float4 per thread; x=128 blocks, ctx=512);
// [640,896): Wq^T 64x64 tiles; [896,1408): Wkv^T; [1408,1664): Wout^T.
__global__ __launch_bounds__(256) void prep(const float* __restrict__ x,
                                            const float* __restrict__ ctx,
                                            const float* __restrict__ Wq,
                                            const float* __restrict__ Wkv,
                                            const float* __restrict__ Wout,
                                            u16* __restrict__ xb,
                                            u16* __restrict__ ctxb,
                                            u16* __restrict__ WqT,
                                            u16* __restrict__ WkvT,
                                            u16* __restrict__ WoutT) {
  int bid = blockIdx.x;
  if (bid < 640) {                         // elementwise cast, 64 elems/thread
    const float* src; u16* dst; int fbase;  // float4 units
    if (bid < 128) { src = x;   dst = xb;   fbase = bid * 4096; }
    else           { src = ctx; dst = ctxb; fbase = (bid - 128) * 4096; }
#pragma unroll
    for (int u = 0; u < 16; ++u) {
      int i = (fbase + u * 256 + threadIdx.x) * 4;
      float4 v = *(const float4*)(src + i);
      uint2 o; o.x = pack2(v.x, v.y); o.y = pack2(v.z, v.w);
      *(uint2*)(dst + i) = o;
    }
    return;
  }
  // transpose+cast W[K][N] -> Wt[N][K], 64x64 tiles
  __shared__ float tile[64][65];           // 16.6 KB
  const float* W; u16* Wt; int K, N, local, ntm;  // ntm = n-tiles mask
  int b2 = bid - 640;
  if (b2 < 256)      { W = Wq;   Wt = WqT;   K = 1024; N = 1024; local = b2;       ntm = 15; }
  else if (b2 < 768) { W = Wkv;  Wt = WkvT;  K = 1024; N = 2048; local = b2 - 256; ntm = 31; }
  else               { W = Wout; Wt = WoutT; K = 1024; N = 1024; local = b2 - 768; ntm = 15; }
  int n0 = (local & ntm) * 64;
  int k0 = (ntm == 15) ? (local >> 4) * 64 : (local >> 5) * 64;
  int tx = threadIdx.x & 63, ty = threadIdx.x >> 6;    // 64 x 4
  for (int i = ty; i < 64; i += 4)
    tile[i][tx] = W[(size_t)(k0 + i) * N + n0 + tx];
  __syncthreads();
  // packed u32 stores: 32 k-pairs x 8 rows per pass -> two 128B runs per wave
  int tx2 = threadIdx.x & 31, ty2 = threadIdx.x >> 5;  // 32 x 8
  for (int j = ty2; j < 64; j += 8)
    *(u32*)&Wt[(size_t)(n0 + j) * K + k0 + tx2 * 2] =
        pack2(tile[tx2 * 2][j], tile[tx2 * 2 + 1][j]);
}

// ---------------- kv projection: 256x256 / BK=64 / FAITHFUL 8-phase schedule ------------
// R8-proven. 2 K-steps per iteration; counted vmcnt(6) only at ph4/ph8; stage ledger
// WAR-safe; every wait's targets >=4 phases old. Epilogues round-1 proven.
__global__ __launch_bounds__(512, 2) void kv_gemm(const u16* __restrict__ ctxb,
                                                  const u16* __restrict__ WkvT,
                                                  u16* __restrict__ kb,
                                                  u16* __restrict__ vTb) {
  __shared__ __align__(16) u16 As[2][256 * 64];   // 64 KiB
  __shared__ __align__(16) u16 Bs[2][256 * 64];   // 64 KiB
  const int tid = threadIdx.x;
  const int lane = tid & 63;
  const int w = tid >> 6;                 // 0..7
  const int wr = w >> 2, wc = w & 3;      // 2 x 4 waves -> wave panel 128M x 64N
  const int l15 = lane & 15, quad = lane >> 4;
  const int K = 1024;

  // XCD-chunked bijective swizzle
  int bid = blockIdx.x;
  int wgid = (bid & 7) * 32 + (bid >> 3);
  const int tm = wgid >> 3, tn = wgid & 7;
  const int m0 = tm * 256, n0 = tn * 256;
  const u16* Ag = ctxb + (size_t)m0 * K;
  const u16* Bg = WkvT + (size_t)n0 * K;

  // per-thread stage source offsets (u16 units): row-reorder + chunk XOR pre-swizzle
  size_t offA[2][2], offB[2][2];
#pragma unroll
  for (int ah = 0; ah < 2; ++ah)
#pragma unroll
    for (int p = 0; p < 2; ++p) {
      int c = p * 512 + (w << 6) + lane;  // chunk id within 16 KiB region
      int s = ah * 128 + (c >> 3);        // LDS slot (reordered row)
      int col = ((c & 7) ^ (s & 7)) << 3; // pre-swizzled source column (bf16)
      int rA = ((s >> 6) & 1) * 128 + ((s >> 7) & 1) * 64 + (s & 63);
      int rB = ((s >> 5) & 3) * 64 + ((s >> 7) & 1) * 32 + (s & 31);
      offA[ah][p] = (size_t)rA * 1024 + col;
      offB[ah][p] = (size_t)rB * 1024 + col;
    }

#define STAGE_A(bufi, ah, kk) do { \
    gload16(Ag + offA[ah][0] + (kk), &As[bufi][(ah) * 8192 + (w << 9)]); \
    gload16(Ag + offA[ah][1] + (kk), &As[bufi][(ah) * 8192 + 4096 + (w << 9)]); \
  } while (0)
#define STAGE_B(bufi, bh, kk) do { \
    gload16(Bg + offB[bh][0] + (kk), &Bs[bufi][(bh) * 8192 + (w << 9)]); \
    gload16(Bg + offB[bh][1] + (kk), &Bs[bufi][(bh) * 8192 + 4096 + (w << 9)]); \
  } while (0)
#define LDA2(dst, i8, bufi) do { \
    const int _s = ((i8) >> 2) * 128 + wr * 64 + ((i8) & 3) * 16 + l15; \
    const u16* _p = &As[bufi][_s * 64]; const int _x = _s & 7; \
    dst[0] = *(const bf16x8*)&_p[(quad ^ _x) << 3]; \
    dst[1] = *(const bf16x8*)&_p[((quad + 4) ^ _x) << 3]; \
  } while (0)
#define LDB2(dst, j, bufi) do { \
    const int _s = ((j) >> 1) * 128 + wc * 32 + ((j) & 1) * 16 + l15; \
    const u16* _p = &Bs[bufi][_s * 64]; const int _x = _s & 7; \
    dst[0] = *(const bf16x8*)&_p[(quad ^ _x) << 3]; \
    dst[1] = *(const bf16x8*)&_p[((quad + 4) ^ _x) << 3]; \
  } while (0)
#define MF(i0, j0, bb) do { \
    _Pragma("unroll") \
    for (int _i = 0; _i < 4; ++_i) { \
      acc[(i0) + _i][(j0)    ] = __builtin_amdgcn_mfma_f32_16x16x32_bf16(a[_i][0], bb[0][0], acc[(i0) + _i][(j0)    ], 0, 0, 0); \
      acc[(i0) + _i][(j0)    ] = __builtin_amdgcn_mfma_f32_16x16x32_bf16(a[_i][1], bb[0][1], acc[(i0) + _i][(j0)    ], 0, 0, 0); \
      acc[(i0) + _i][(j0) + 1] = __builtin_amdgcn_mfma_f32_16x16x32_bf16(a[_i][0], bb[1][0], acc[(i0) + _i][(j0) + 1], 0, 0, 0); \
      acc[(i0) + _i][(j0) + 1] = __builtin_amdgcn_mfma_f32_16x16x32_bf16(a[_i][1], bb[1][1], acc[(i0) + _i][(j0) + 1], 0, 0, 0); \
    } \
  } while (0)
#define BAR()   __builtin_amdgcn_s_barrier()
#define LGKM0() asm volatile("s_waitcnt lgkmcnt(0)" ::: "memory")

  f32x4 acc[8][4] = {};
  bf16x8 a[4][2], b[2][2], c2[2][2];

  // prologue: step0 full (Aa,Ba,Bb,Ab) + step1 trio (Aa,Ba,Bb) = 14 loads
  STAGE_A(0, 0, 0);
  STAGE_B(0, 0, 0);
  STAGE_B(0, 1, 0);
  STAGE_A(0, 1, 0);
  STAGE_A(1, 0, 64);
  STAGE_B(1, 0, 64);
  STAGE_B(1, 1, 64);
  asm volatile("s_waitcnt vmcnt(6)" ::: "memory");   // step0's 8 loads complete
  BAR();

#define HALF(bufi, kAb, kNext, STG, WMID, WEND) do { \
    LDB2(b[0], 0, bufi); LDB2(b[1], 1, bufi); \
    LDA2(a[0], 0, bufi); LDA2(a[1], 1, bufi); LDA2(a[2], 2, bufi); LDA2(a[3], 3, bufi); \
    if (kAb >= 0) STAGE_A((bufi) ^ 1, 1, kAb); \
    BAR(); LGKM0(); \
    __builtin_amdgcn_s_setprio(1); MF(0, 0, b); __builtin_amdgcn_s_setprio(0); \
    BAR(); \
    LDB2(c2[0], 2, bufi); LDB2(c2[1], 3, bufi); \
    if (STG) STAGE_A(bufi, 0, kNext); \
    BAR(); LGKM0(); \
    __builtin_amdgcn_s_setprio(1); MF(0, 2, c2); __builtin_amdgcn_s_setprio(0); \
    BAR(); \
    LDA2(a[0], 4, bufi); LDA2(a[1], 5, bufi); LDA2(a[2], 6, bufi); LDA2(a[3], 7, bufi); \
    if (STG) STAGE_B(bufi, 0, kNext); \
    BAR(); LGKM0(); \
    __builtin_amdgcn_s_setprio(1); MF(4, 0, b); __builtin_amdgcn_s_setprio(0); \
    BAR(); \
    if (STG) STAGE_B(bufi, 1, kNext); \
    BAR(); \
    __builtin_amdgcn_s_setprio(1); MF(4, 2, c2); __builtin_amdgcn_s_setprio(0); \
    WMID; \
    BAR(); \
  } while (0)

  for (int i = 0; i < 7; ++i) {
    const int k2 = i * 128;
    HALF(0, k2 + 64, k2 + 128, 1,
         asm volatile("s_waitcnt vmcnt(6)" ::: "memory"), );
    HALF(1, k2 + 128, k2 + 192, 1,
         asm volatile("s_waitcnt vmcnt(6)" ::: "memory"), );
  }
  HALF(0, 960, 0, 0,
       asm volatile("s_waitcnt vmcnt(0)" ::: "memory"), );
  HALF(1, -1, 0, 0, , );

#undef HALF
#undef BAR
#undef LGKM0

  // epilogue (round-1 proven): tn<4 -> K row-major, tn>=4 -> V transposed scatter
  if (tn < 4) {
#pragma unroll
    for (int i8 = 0; i8 < 8; ++i8)
#pragma unroll
      for (int j = 0; j < 4; ++j) {
        int col = n0 + wc * 64 + j * 16 + l15;
#pragma unroll
        for (int r = 0; r < 4; ++r) {
          int row = m0 + wr * 128 + i8 * 16 + quad * 4 + r;
          kb[(size_t)row * 1024 + col] = f2bf(acc[i8][j][r]);
        }
      }
  } else {
    const int bb_ = m0 >> 12;
#pragma unroll
    for (int i8 = 0; i8 < 8; ++i8) {
      int kvr = (m0 & 4095) + wr * 128 + i8 * 16 + quad * 4;
#pragma unroll
      for (int j = 0; j < 4; ++j) {
        int c = (n0 - 1024) + wc * 64 + j * 16 + l15;
        int h = c >> 6, dh = c & 63;
        uint2 st;
        st.x = pack2(acc[i8][j][0], acc[i8][j][1]);
        st.y = pack2(acc[i8][j][2], acc[i8][j][3]);
        *(uint2*)&vTb[((size_t)((bb_ * 16 + h) * 64 + dh)) * NKV_ + kvr] = st;
      }
    }
  }
#undef STAGE_A
#undef STAGE_B
#undef LDA2
#undef LDB2
#undef MF
}

// ---------------- out-proj GEMM: 64x128 tiles, tri-buffered counted-vmcnt pipeline ------
__global__ __launch_bounds__(256) void out_gemm(const u16* __restrict__ A,
                                                const u16* __restrict__ Bt,
                                                float* __restrict__ Cout,
                                                const float* __restrict__ bias) {
  __shared__ __align__(16) u16 As[3][64 * 32];    // 12 KB
  __shared__ __align__(16) u16 Bs[3][128 * 32];   // 24 KB
  const int tid = threadIdx.x;
  const int lane = tid & 63;
  const int w = tid >> 6;
  const int wr = w >> 1, wc = w & 1;           // wave covers 32M x 64N
  const int l15 = lane & 15, quad = lane >> 4;
  const int unit = blockIdx.x;
  const int m0 = (unit >> 3) * 64, n0 = (unit & 7) * 128;
  const int K = 1024, N = 1024;

  const u16* Ab = A + (size_t)m0 * K;
  const u16* Bb = Bt + (size_t)n0 * K;
  f32x4 acc[2][4] = {};

  const int ar = tid >> 2, ac = (tid & 3) << 3;          // A: 256 chunks, 1/thread
  const int q1 = w * 64 + lane, q2 = q1 + 256;           // B: 512 chunks, 2/thread
  const int br1 = q1 >> 2, bc1 = (q1 & 3) << 3;
  const int br2 = q2 >> 2, bc2 = (q2 & 3) << 3;

#define STG(bi, k0) do { \
    gload16(Ab + (size_t)ar * K + (k0) + ac, &As[bi][w * 512]); \
    gload16(Bb + (size_t)br1 * K + (k0) + bc1, &Bs[bi][w * 512]); \
    gload16(Bb + (size_t)br2 * K + (k0) + bc2, &Bs[bi][2048 + w * 512]); \
  } while (0)

  STG(0, 0);
  STG(1, 32);
  asm volatile("s_waitcnt vmcnt(3)" ::: "memory");   // STG(0) complete, STG(1) in flight
  __builtin_amdgcn_s_barrier();

  for (int it = 0; it < 32; ++it) {
    const int cur = it % 3;
    bf16x8 af[2], bfr[4];
#pragma unroll
    for (int i = 0; i < 2; ++i)
      af[i] = *(const bf16x8*)&As[cur][(wr * 32 + i * 16 + l15) * 32 + quad * 8];
#pragma unroll
    for (int j = 0; j < 4; ++j)
      bfr[j] = *(const bf16x8*)&Bs[cur][(wc * 64 + j * 16 + l15) * 32 + quad * 8];
    if (it + 2 < 32) STG((it + 2) % 3, (it + 2) * 32);
    __builtin_amdgcn_s_barrier();
    asm volatile("s_waitcnt lgkmcnt(0)" ::: "memory");
    __builtin_amdgcn_s_setprio(1);
#pragma unroll
    for (int i = 0; i < 2; ++i)
#pragma unroll
      for (int j = 0; j < 4; ++j)
        acc[i][j] = __builtin_amdgcn_mfma_f32_16x16x32_bf16(af[i], bfr[j], acc[i][j], 0, 0, 0);
    __builtin_amdgcn_s_setprio(0);
    if (it + 2 < 32)      { asm volatile("s_waitcnt vmcnt(3)" ::: "memory"); }
    else if (it + 2 == 32){ asm volatile("s_waitcnt vmcnt(0)" ::: "memory"); }
    __builtin_amdgcn_s_barrier();
  }
#undef STG

#pragma unroll
  for (int i = 0; i < 2; ++i)
#pragma unroll
    for (int j = 0; j < 4; ++j) {
      int col = n0 + wc * 64 + j * 16 + l15;
      float bv = bias[col];
#pragma unroll
      for (int r = 0; r < 4; ++r) {
        int row = m0 + wr * 32 + i * 16 + quad * 4 + r;
        Cout[(size_t)row * N + col] = acc[i][j][r] + bv;
      }
    }
}

// ---------------- flash attention + fused Q-projection (R12-proven) ---------------------
// Epilogue barrier-halving: after the main loop Ks/Vs/P32 are dead; use them as three
// 16 KB reduce buffers so O-slices d=0,1,2 reduce in ONE barrier pair and d=3 in a
// second (4 barriers vs 8). cvt_pk replaces scalar packs in prologue qf and epilogue.
__global__ __launch_bounds__(256, 2) void attn_kernel(const u16* __restrict__ xb,
                                                      const u16* __restrict__ WqT,
                                                      const u16* __restrict__ kb,
                                                      const u16* __restrict__ vT,
                                                      u16* __restrict__ attn_out) {
  __shared__ __align__(16) u16 Ks[128 * 64];       // [kv][dh], 16B groups XOR-swizzled
  __shared__ __align__(16) u16 Vs[64 * 128];       // [dh][kv], XOR-swizzled (16 groups/row)
  __shared__ __align__(16) u32 P32[4 * 4 * 16 * 20]; // [w][t][q=l15][20]: wave-private pairs
  __shared__ float Lr[4][4][16];                   // [w][t][q] partial l

  const int tid = threadIdx.x;
  const int lane = tid & 63;
  const int w = tid >> 6;
  const int l15 = lane & 15, quad = lane >> 4;
  const int bh = blockIdx.x, b = bh >> 4, h = bh & 15;
  const int q0 = blockIdx.y * 64;

  const float SC = 0.125f * 1.44269504088896340736f;   // dh^-0.5 * log2(e)
  union { u16 s[8]; u32 u[4]; bf16x8 v; } qf[4][2];

  // ---- Q-projection prologue (double-buffered, R12-proven) ----
  {
    const u16* Axb = xb + (size_t)(b * NQ_ + q0) * 1024;     // 64 rows of x (bf16)
    const u16* Bwq = WqT + (size_t)(h * 64) * 1024;          // 64 Wq-columns
    const int c1 = tid, c2 = tid + 256;
    const int r1 = c1 >> 3, g1 = c1 & 7;
    const int r2 = c2 >> 3, g2 = c2 & 7;
    const size_t sO1 = (size_t)r1 * 1024 + (size_t)((g1 ^ (r1 & 7)) << 3);
    const size_t sO2 = (size_t)r2 * 1024 + (size_t)((g2 ^ (r2 & 7)) << 3);
    f32x4 qacc[4] = {};
    const int x7 = l15 & 7;

#define QSTG(dst, kk) do { \
      gload16(Axb + sO1 + (kk), &dst[w * 512]); \
      gload16(Axb + sO2 + (kk), &dst[2048 + w * 512]); \
      gload16(Bwq + sO1 + (kk), &dst[4096 + w * 512]); \
      gload16(Bwq + sO2 + (kk), &dst[6144 + w * 512]); \
    } while (0)

#define QSTEP(dst, kk, DOSTG, W4, W0) do { \
      bf16x8 af_[2], bfr_[4][2]; \
      _Pragma("unroll") \
      for (int kc = 0; kc < 2; ++kc) { \
        af_[kc] = *(const bf16x8*)&dst[(w * 16 + l15) * 64 + (((kc * 4 + quad) ^ x7) << 3)]; \
        _Pragma("unroll") \
        for (int j = 0; j < 4; ++j) \
          bfr_[j][kc] = *(const bf16x8*) \
            &dst[4096 + (j * 16 + l15) * 64 + (((kc * 4 + quad) ^ x7) << 3)]; \
      } \
      asm volatile("s_waitcnt lgkmcnt(0)" ::: "memory"); \
      __builtin_amdgcn_s_barrier(); \
      if (DOSTG) QSTG(dst, kk); \
      _Pragma("unroll") \
      for (int j = 0; j < 4; ++j) { \
        qacc[j] = __builtin_amdgcn_mfma_f32_16x16x32_bf16(af_[0], bfr_[j][0], qacc[j], 0, 0, 0); \
        qacc[j] = __builtin_amdgcn_mfma_f32_16x16x32_bf16(af_[1], bfr_[j][1], qacc[j], 0, 0, 0); \
      } \
      if (W4)      { asm volatile("s_waitcnt vmcnt(4)" ::: "memory"); } \
      else if (W0) { asm volatile("s_waitcnt vmcnt(0)" ::: "memory"); } \
      __builtin_amdgcn_s_barrier(); \
    } while (0)

    QSTG(Ks, 0);
    QSTG(Vs, 64);
    asm volatile("s_waitcnt vmcnt(4)" ::: "memory");   // Ks's 4 complete, Vs in flight
    __builtin_amdgcn_s_barrier();
#pragma unroll
    for (int i = 0; i < 16; i += 2) {
      QSTEP(Ks, (i + 2) * 64, (i + 2) < 16, (i + 2) < 16, (i + 2) == 16);
      QSTEP(Vs, (i + 3) * 64, (i + 3) < 16, (i + 3) < 16, 0);
    }
#undef QSTG
#undef QSTEP

    // bounce: P32 as 64x64 f32, col' = col ^ ((row&7)*8)
    float* Q64 = (float*)P32;
#pragma unroll
    for (int j = 0; j < 4; ++j)
#pragma unroll
      for (int r = 0; r < 4; ++r) {
        int row = w * 16 + quad * 4 + r;
        Q64[row * 64 + ((j * 16 + l15) ^ ((row & 7) * 8))] = qacc[j][r];
      }
    __syncthreads();
#pragma unroll
    for (int t = 0; t < 4; ++t)
#pragma unroll
      for (int kc = 0; kc < 2; ++kc) {
        const float* qp = Q64 + (t * 16 + l15) * 64 + (((kc * 4 + quad) ^ x7) * 8);
        f32x4 lo = *(const f32x4*)qp;
        f32x4 hi = *(const f32x4*)(qp + 4);
        qf[t][kc].u[0] = cvtpk(lo[0] * SC, lo[1] * SC);
        qf[t][kc].u[1] = cvtpk(lo[2] * SC, lo[3] * SC);
        qf[t][kc].u[2] = cvtpk(hi[0] * SC, hi[1] * SC);
        qf[t][kc].u[3] = cvtpk(hi[2] * SC, hi[3] * SC);
      }
    __syncthreads();   // all qf reads done before main loop reuses P32
  }

#define STAGEKV(j0) do { \
    _Pragma("unroll") \
    for (int i_ = 0; i_ < 4; ++i_) { \
      int s_ = i_ * 256 + tid; \
      int kr = s_ >> 3, kg = (s_ ^ kr) & 7; \
      gload16(kb + (size_t)(b * NKV_ + (j0) + kr) * 1024 + h * 64 + kg * 8, \
              &Ks[(i_ * 256 + w * 64) * 8]); \
      int vr = s_ >> 4, vg = (s_ ^ vr) & 15; \
      gload16(vT + (size_t)(bh * 64 + vr) * NKV_ + (j0) + vg * 8, \
              &Vs[(i_ * 256 + w * 64) * 8]); \
    } \
  } while (0)

  f32x4 Oacc[4][4] = {};
  float l_lane[4] = {0.f, 0.f, 0.f, 0.f};

  STAGEKV(0);                                // prologue: tile 0

  for (int it = 0; it < 32; ++it) {
    __syncthreads();                         // tile `it` staged (vmcnt drained per-wave)

    // fragment reads for tile `it` (this wave's complete K/V consumption)
    bf16x8 kf[2][2];
#pragma unroll
    for (int kvt = 0; kvt < 2; ++kvt)
#pragma unroll
      for (int kc = 0; kc < 2; ++kc)
        kf[kvt][kc] = *(const bf16x8*)
          &Ks[(w * 32 + kvt * 16 + l15) * 64 + (((kc * 4 + quad) ^ l15) & 7) * 8];
    bf16x8 vf[4];
#pragma unroll
    for (int d = 0; d < 4; ++d)
      vf[d] = *(const bf16x8*)
        &Vs[(d * 16 + l15) * 128 + (((w * 4 + quad) ^ l15) & 15) * 8];

    __syncthreads();                         // all waves done reading Ks/Vs

    if (it < 31) STAGEKV((it + 1) * 128);    // overwrite: overlaps full compute below

    f32x4 sacc[2][4] = {};
    __builtin_amdgcn_s_setprio(1);
#pragma unroll
    for (int kvt = 0; kvt < 2; ++kvt)
#pragma unroll
      for (int t = 0; t < 4; ++t)
#pragma unroll
        for (int kc = 0; kc < 2; ++kc)
          sacc[kvt][t] = __builtin_amdgcn_mfma_f32_16x16x32_bf16(
              kf[kvt][kc], qf[t][kc].v, sacc[kvt][t], 0, 0, 0);
    __builtin_amdgcn_s_setprio(0);

#pragma unroll
    for (int kvt = 0; kvt < 2; ++kvt)
#pragma unroll
      for (int t = 0; t < 4; ++t) {
        float p0 = __builtin_amdgcn_exp2f(sacc[kvt][t][0]);
        float p1 = __builtin_amdgcn_exp2f(sacc[kvt][t][1]);
        float p2 = __builtin_amdgcn_exp2f(sacc[kvt][t][2]);
        float p3 = __builtin_amdgcn_exp2f(sacc[kvt][t][3]);
        l_lane[t] += (p0 + p1) + (p2 + p3);
        uint2 pk; pk.x = cvtpk(p0, p1); pk.y = cvtpk(p2, p3);
        *(uint2*)&P32[((w * 4 + t) * 16 + l15) * 20 + kvt * 8 + quad * 2] = pk;
      }

    bf16x8 pf[4];
#pragma unroll
    for (int t = 0; t < 4; ++t)
      pf[t] = *(const bf16x8*)&P32[((w * 4 + t) * 16 + l15) * 20 + quad * 4];
    __builtin_amdgcn_s_setprio(1);
#pragma unroll
    for (int d = 0; d < 4; ++d)
#pragma unroll
      for (int t = 0; t < 4; ++t)
        Oacc[d][t] = __builtin_amdgcn_mfma_f32_16x16x32_bf16(vf[d], pf[t], Oacc[d][t],
                                                             0, 0, 0);
    __builtin_amdgcn_s_setprio(0);
  }
#undef STAGEKV

#pragma unroll
  for (int t = 0; t < 4; ++t) {
    l_lane[t] += __shfl_xor(l_lane[t], 16);
    l_lane[t] += __shfl_xor(l_lane[t], 32);
  }
  if (quad == 0) {
#pragma unroll
    for (int t = 0; t < 4; ++t) Lr[w][t][l15] = l_lane[t];
  }
  __syncthreads();                    // Lr ready; Ks/Vs/P32 all dead -> reduce buffers
  float inv = 1.0f / (Lr[0][w][l15] + Lr[1][w][l15] + Lr[2][w][l15] + Lr[3][w][l15]);

  float* R0 = (float*)Ks;             // 16 KB each; slice = 16*256 f32 = 16 KB
  float* R1 = (float*)Vs;
  float* R2 = (float*)P32;
  u16* ob = attn_out + (size_t)(b * NQ_ + q0 + w * 16 + l15) * INNER_ + h * 64;
  const int wi = quad * 64 + l15 * 4;

  // pass 1: slices d=0,1,2
#pragma unroll
  for (int t = 0; t < 4; ++t) {
    *(f32x4*)&R0[(w * 4 + t) * 256 + wi] = Oacc[0][t];
    *(f32x4*)&R1[(w * 4 + t) * 256 + wi] = Oacc[1][t];
    *(f32x4*)&R2[(w * 4 + t) * 256 + wi] = Oacc[2][t];
  }
  __syncthreads();
  {
    f32x4 r0 = *(const f32x4*)&R0[w * 256 + wi];
    f32x4 r1 = *(const f32x4*)&R1[w * 256 + wi];
    f32x4 r2 = *(const f32x4*)&R2[w * 256 + wi];
#pragma unroll
    for (int ww = 1; ww < 4; ++ww) {
      f32x4 c0 = *(const f32x4*)&R0[(ww * 4 + w) * 256 + wi];
      f32x4 c1 = *(const f32x4*)&R1[(ww * 4 + w) * 256 + wi];
      f32x4 c2 = *(const f32x4*)&R2[(ww * 4 + w) * 256 + wi];
#pragma unroll
      for (int e = 0; e < 4; ++e) { r0[e] += c0[e]; r1[e] += c1[e]; r2[e] += c2[e]; }
    }
    *(u32*)(ob + 0 * 16 + quad * 4)     = cvtpk(r0[0] * inv, r0[1] * inv);
    *(u32*)(ob + 0 * 16 + quad * 4 + 2) = cvtpk(r0[2] * inv, r0[3] * inv);
    *(u32*)(ob + 1 * 16 + quad * 4)     = cvtpk(r1[0] * inv, r1[1] * inv);
    *(u32*)(ob + 1 * 16 + quad * 4 + 2) = cvtpk(r1[2] * inv, r1[3] * inv);
    *(u32*)(ob + 2 * 16 + quad * 4)     = cvtpk(r2[0] * inv, r2[1] * inv);
    *(u32*)(ob + 2 * 16 + quad * 4 + 2) = cvtpk(r2[2] * inv, r2[3] * inv);
  }
  __syncthreads();
  // pass 2: slice d=3
#pragma unroll
  for (int t = 0; t < 4; ++t)
    *(f32x4*)&R0[(w * 4 + t) * 256 + wi] = Oacc[3][t];
  __syncthreads();
  {
    f32x4 r = *(const f32x4*)&R0[w * 256 + wi];
#pragma unroll
    for (int ww = 1; ww < 4; ++ww) {
      f32x4 c = *(const f32x4*)&R0[(ww * 4 + w) * 256 + wi];
#pragma unroll
      for (int e = 0; e < 4; ++e) r[e] += c[e];
    }
    *(u32*)(ob + 3 * 16 + quad * 4)     = cvtpk(r[0] * inv, r[1] * inv);
    *(u32*)(ob + 3 * 16 + quad * 4 + 2) = cvtpk(r[2] * inv, r[3] * inv);
  }
}

// ---------------- driver ----------------
extern "C" void kernel_launch(void* const* d_in, const int* in_sizes, int n_in,
                              void* d_out, int out_size, void* d_ws, size_t ws_size,
                              hipStream_t stream) {
  const float* x    = (const float*)d_in[0];
  const float* ctx  = (const float*)d_in[1];
  const float* Wq   = (const float*)d_in[2];
  const float* Wkv  = (const float*)d_in[3];
  const float* Wout = (const float*)d_in[4];
  const float* bout = (const float*)d_in[5];

  char* ws = (char*)d_ws;
  u16* xb    = (u16*)(ws + (size_t)( 0u << 20));  // 4 MB  [live through attn prologue]
  u16* ctxb  = (u16*)(ws + (size_t)( 4u << 20));  // 16 MB [dead after kv_gemm]
  u16* WqT   = (u16*)(ws + (size_t)(20u << 20));  // 2 MB  [live through attn prologue]
  u16* WkvT  = (u16*)(ws + (size_t)(22u << 20));  // 4 MB
  u16* WoutT = (u16*)(ws + (size_t)(26u << 20));  // 2 MB
  u16* ab    = (u16*)(ws + (size_t)(28u << 20));  // 4 MB  [old qb slot; NOT aliasing xb]
  u16* kb    = (u16*)(ws + (size_t)(32u << 20));  // 16 MB (K row-major bf16)
  u16* vTb   = (u16*)(ws + (size_t)(48u << 20));  // 16 MB (V transposed [bh*64+dh][NKV])

  // casts + weight transposes in one dispatch (64x64 transpose tiles, fat casts)
  prep<<<1664, 256, 0, stream>>>(x, ctx, Wq, Wkv, Wout, xb, ctxb, WqT, WkvT, WoutT);
  // kv projection: 256 blocks of 256x256, faithful 8-phase, 1 block/CU
  kv_gemm<<<256, 512, 0, stream>>>(ctxb, WkvT, kb, vTb);
  // fused q-projection + softmax attention: 512 blocks x 256 threads
  attn_kernel<<<dim3(32, 16), 256, 0, stream>>>(xb, WqT, kb, vTb, ab);
  // out = attn Wout + b_out : fp32, 256 blocks, tri-buffered pipeline
  out_gemm<<<256, 256, 0, stream>>>(ab, WoutT, (float*)d_out, bout);
}

// Round 14
// 204.077 us; speedup vs baseline: 1.0247x; 1.0053x over previous
//
#include <hip/hip_runtime.h>
#include <stdint.h>

// Problem constants
#define B_    2
#define NQ_   1024
#define NKV_  4096
#define DQ_   1024
#define H_    16
#define DH_   64
#define INNER_ 1024

typedef unsigned short u16;
typedef uint32_t u32;
typedef __bf16 bf16x8 __attribute__((ext_vector_type(8)));
typedef float  f32x4  __attribute__((ext_vector_type(4)));

__device__ __forceinline__ u16 f2bf(float x) {           // RNE
  union { float f; uint32_t u; } v; v.f = x;
  uint32_t r = v.u + 0x7FFFu + ((v.u >> 16) & 1u);
  return (u16)(r >> 16);
}
__device__ __forceinline__ u32 pack2(float a, float b) { // RNE pair
  return (u32)f2bf(a) | ((u32)f2bf(b) << 16);
}
__device__ __forceinline__ u32 cvtpk(float lo, float hi) { // 1-VALU packed cvt (RNE)
  u32 r;
  asm("v_cvt_pk_bf16_f32 %0, %1, %2" : "=v"(r) : "v"(lo), "v"(hi));
  return r;
}
__device__ __forceinline__ float bf2f(u16 s) {
  union { float f; uint32_t u; } v; v.u = ((uint32_t)s) << 16; return v.f;
}

// async global->LDS, 16B/lane; lds base wave-uniform, hw adds lane*16
__device__ __forceinline__ void gload16(const void* g, void* l) {
  __builtin_amdgcn_global_load_lds((const __attribute__((address_space(1))) void*)g,
                                   (__attribute__((address_space(3))) void*)l,
                                   16, 0, 0);
}

// ---------------- fused prep: casts + weight transposes in ONE dispatch -----------------
// blocks [0,640): fat casts (16 x float4 per thread; x=128 blocks, ctx=512);
// [640,896): Wq^T 64x64 tiles; [896,1408): Wkv^T; [1408,1664): Wout^T.
__global__ __launch_bounds__(256) void prep(const float* __restrict__ x,
                                            const float* __restrict__ ctx,
                                            const float* __restrict__ Wq,
                                            const float* __restrict__ Wkv,
                                            const float* __restrict__ Wout,
                                            u16* __restrict__ xb,
                                            u16* __restrict__ ctxb,
                                            u16* __restrict__ WqT,
                                            u16* __restrict__ WkvT,
                                            u16* __restrict__ WoutT) {
  int bid = blockIdx.x;
  if (bid < 640) {                         // elementwise cast, 64 elems/thread
    const float* src; u16* dst; int fbase;  // float4 units
    if (bid < 128) { src = x;   dst = xb;   fbase = bid * 4096; }
    else           { src = ctx; dst = ctxb; fbase = (bid - 128) * 4096; }
#pragma unroll
    for (int u = 0; u < 16; ++u) {
      int i = (fbase + u * 256 + threadIdx.x) * 4;
      float4 v = *(const float4*)(src + i);
      uint2 o; o.x = pack2(v.x, v.y); o.y = pack2(v.z, v.w);
      *(uint2*)(dst + i) = o;
    }
    return;
  }
  // transpose+cast W[K][N] -> Wt[N][K], 64x64 tiles
  __shared__ float tile[64][65];           // 16.6 KB
  const float* W; u16* Wt; int K, N, local, ntm;  // ntm = n-tiles mask
  int b2 = bid - 640;
  if (b2 < 256)      { W = Wq;   Wt = WqT;   K = 1024; N = 1024; local = b2;       ntm = 15; }
  else if (b2 < 768) { W = Wkv;  Wt = WkvT;  K = 1024; N = 2048; local = b2 - 256; ntm = 31; }
  else               { W = Wout; Wt = WoutT; K = 1024; N = 1024; local = b2 - 768; ntm = 15; }
  int n0 = (local & ntm) * 64;
  int k0 = (ntm == 15) ? (local >> 4) * 64 : (local >> 5) * 64;
  int tx = threadIdx.x & 63, ty = threadIdx.x >> 6;    // 64 x 4
  for (int i = ty; i < 64; i += 4)
    tile[i][tx] = W[(size_t)(k0 + i) * N + n0 + tx];
  __syncthreads();
  // packed u32 stores: 32 k-pairs x 8 rows per pass -> two 128B runs per wave
  int tx2 = threadIdx.x & 31, ty2 = threadIdx.x >> 5;  // 32 x 8
  for (int j = ty2; j < 64; j += 8)
    *(u32*)&Wt[(size_t)(n0 + j) * K + k0 + tx2 * 2] =
        pack2(tile[tx2 * 2][j], tile[tx2 * 2 + 1][j]);
}

// ---------------- kv projection: 256x256 / BK=64 / FAITHFUL 8-phase schedule ------------
// R8-proven main loop. NEW (R14): epilogue LDS-bounce — As/Bs (128 KB, dead after the
// final barrier) hold the 256x256 bf16 output tile (row p, pos s; group-of-8 XOR swizzle
// s' = (s>>3 ^ (p&7))*8 + (s&7)); after one barrier each thread emits 16 coalesced
// dwordx4 stores in 512B runs (vs 128 scalar / 32 line-scattered stores before).
__global__ __launch_bounds__(512, 2) void kv_gemm(const u16* __restrict__ ctxb,
                                                  const u16* __restrict__ WkvT,
                                                  u16* __restrict__ kb,
                                                  u16* __restrict__ vTb) {
  __shared__ __align__(16) u16 As[2][256 * 64];   // 64 KiB
  __shared__ __align__(16) u16 Bs[2][256 * 64];   // 64 KiB
  const int tid = threadIdx.x;
  const int lane = tid & 63;
  const int w = tid >> 6;                 // 0..7
  const int wr = w >> 2, wc = w & 3;      // 2 x 4 waves -> wave panel 128M x 64N
  const int l15 = lane & 15, quad = lane >> 4;
  const int K = 1024;

  // XCD-chunked bijective swizzle
  int bid = blockIdx.x;
  int wgid = (bid & 7) * 32 + (bid >> 3);
  const int tm = wgid >> 3, tn = wgid & 7;
  const int m0 = tm * 256, n0 = tn * 256;
  const u16* Ag = ctxb + (size_t)m0 * K;
  const u16* Bg = WkvT + (size_t)n0 * K;

  // per-thread stage source offsets (u16 units): row-reorder + chunk XOR pre-swizzle
  size_t offA[2][2], offB[2][2];
#pragma unroll
  for (int ah = 0; ah < 2; ++ah)
#pragma unroll
    for (int p = 0; p < 2; ++p) {
      int c = p * 512 + (w << 6) + lane;  // chunk id within 16 KiB region
      int s = ah * 128 + (c >> 3);        // LDS slot (reordered row)
      int col = ((c & 7) ^ (s & 7)) << 3; // pre-swizzled source column (bf16)
      int rA = ((s >> 6) & 1) * 128 + ((s >> 7) & 1) * 64 + (s & 63);
      int rB = ((s >> 5) & 3) * 64 + ((s >> 7) & 1) * 32 + (s & 31);
      offA[ah][p] = (size_t)rA * 1024 + col;
      offB[ah][p] = (size_t)rB * 1024 + col;
    }

#define STAGE_A(bufi, ah, kk) do { \
    gload16(Ag + offA[ah][0] + (kk), &As[bufi][(ah) * 8192 + (w << 9)]); \
    gload16(Ag + offA[ah][1] + (kk), &As[bufi][(ah) * 8192 + 4096 + (w << 9)]); \
  } while (0)
#define STAGE_B(bufi, bh, kk) do { \
    gload16(Bg + offB[bh][0] + (kk), &Bs[bufi][(bh) * 8192 + (w << 9)]); \
    gload16(Bg + offB[bh][1] + (kk), &Bs[bufi][(bh) * 8192 + 4096 + (w << 9)]); \
  } while (0)
#define LDA2(dst, i8, bufi) do { \
    const int _s = ((i8) >> 2) * 128 + wr * 64 + ((i8) & 3) * 16 + l15; \
    const u16* _p = &As[bufi][_s * 64]; const int _x = _s & 7; \
    dst[0] = *(const bf16x8*)&_p[(quad ^ _x) << 3]; \
    dst[1] = *(const bf16x8*)&_p[((quad + 4) ^ _x) << 3]; \
  } while (0)
#define LDB2(dst, j, bufi) do { \
    const int _s = ((j) >> 1) * 128 + wc * 32 + ((j) & 1) * 16 + l15; \
    const u16* _p = &Bs[bufi][_s * 64]; const int _x = _s & 7; \
    dst[0] = *(const bf16x8*)&_p[(quad ^ _x) << 3]; \
    dst[1] = *(const bf16x8*)&_p[((quad + 4) ^ _x) << 3]; \
  } while (0)
#define MF(i0, j0, bb) do { \
    _Pragma("unroll") \
    for (int _i = 0; _i < 4; ++_i) { \
      acc[(i0) + _i][(j0)    ] = __builtin_amdgcn_mfma_f32_16x16x32_bf16(a[_i][0], bb[0][0], acc[(i0) + _i][(j0)    ], 0, 0, 0); \
      acc[(i0) + _i][(j0)    ] = __builtin_amdgcn_mfma_f32_16x16x32_bf16(a[_i][1], bb[0][1], acc[(i0) + _i][(j0)    ], 0, 0, 0); \
      acc[(i0) + _i][(j0) + 1] = __builtin_amdgcn_mfma_f32_16x16x32_bf16(a[_i][0], bb[1][0], acc[(i0) + _i][(j0) + 1], 0, 0, 0); \
      acc[(i0) + _i][(j0) + 1] = __builtin_amdgcn_mfma_f32_16x16x32_bf16(a[_i][1], bb[1][1], acc[(i0) + _i][(j0) + 1], 0, 0, 0); \
    } \
  } while (0)
#define BAR()   __builtin_amdgcn_s_barrier()
#define LGKM0() asm volatile("s_waitcnt lgkmcnt(0)" ::: "memory")

  f32x4 acc[8][4] = {};
  bf16x8 a[4][2], b[2][2], c2[2][2];

  // prologue: step0 full (Aa,Ba,Bb,Ab) + step1 trio (Aa,Ba,Bb) = 14 loads
  STAGE_A(0, 0, 0);
  STAGE_B(0, 0, 0);
  STAGE_B(0, 1, 0);
  STAGE_A(0, 1, 0);
  STAGE_A(1, 0, 64);
  STAGE_B(1, 0, 64);
  STAGE_B(1, 1, 64);
  asm volatile("s_waitcnt vmcnt(6)" ::: "memory");   // step0's 8 loads complete
  BAR();

#define HALF(bufi, kAb, kNext, STG, WMID, WEND) do { \
    LDB2(b[0], 0, bufi); LDB2(b[1], 1, bufi); \
    LDA2(a[0], 0, bufi); LDA2(a[1], 1, bufi); LDA2(a[2], 2, bufi); LDA2(a[3], 3, bufi); \
    if (kAb >= 0) STAGE_A((bufi) ^ 1, 1, kAb); \
    BAR(); LGKM0(); \
    __builtin_amdgcn_s_setprio(1); MF(0, 0, b); __builtin_amdgcn_s_setprio(0); \
    BAR(); \
    LDB2(c2[0], 2, bufi); LDB2(c2[1], 3, bufi); \
    if (STG) STAGE_A(bufi, 0, kNext); \
    BAR(); LGKM0(); \
    __builtin_amdgcn_s_setprio(1); MF(0, 2, c2); __builtin_amdgcn_s_setprio(0); \
    BAR(); \
    LDA2(a[0], 4, bufi); LDA2(a[1], 5, bufi); LDA2(a[2], 6, bufi); LDA2(a[3], 7, bufi); \
    if (STG) STAGE_B(bufi, 0, kNext); \
    BAR(); LGKM0(); \
    __builtin_amdgcn_s_setprio(1); MF(4, 0, b); __builtin_amdgcn_s_setprio(0); \
    BAR(); \
    if (STG) STAGE_B(bufi, 1, kNext); \
    BAR(); \
    __builtin_amdgcn_s_setprio(1); MF(4, 2, c2); __builtin_amdgcn_s_setprio(0); \
    WMID; \
    BAR(); \
  } while (0)

  for (int i = 0; i < 7; ++i) {
    const int k2 = i * 128;
    HALF(0, k2 + 64, k2 + 128, 1,
         asm volatile("s_waitcnt vmcnt(6)" ::: "memory"), );
    HALF(1, k2 + 128, k2 + 192, 1,
         asm volatile("s_waitcnt vmcnt(6)" ::: "memory"), );
  }
  HALF(0, 960, 0, 0,
       asm volatile("s_waitcnt vmcnt(0)" ::: "memory"), );
  HALF(1, -1, 0, 0, , );

#undef HALF
#undef BAR
#undef LGKM0

  // ---- epilogue: LDS-bounce (As/Bs dead after final barrier; 128 KB = full tile) ----
  // overlay row p in [0,256): p<128 -> As-block, else Bs-block (256 u16 per row)
  u16* baseA = &As[0][0];
  u16* baseB = &Bs[0][0];
#define ROWP(p) ((p) < 128 ? baseA + (p) * 256 : baseB + ((p) - 128) * 256)

  if (tn < 4) {
    // K: p = output row (kv), s = col within 256-block
#pragma unroll
    for (int i8 = 0; i8 < 8; ++i8)
#pragma unroll
      for (int j = 0; j < 4; ++j) {
        const int s = wc * 64 + j * 16 + l15;
        const int sg = s >> 3, so = s & 7;
#pragma unroll
        for (int r = 0; r < 4; ++r) {
          const int p = wr * 128 + i8 * 16 + quad * 4 + r;
          ROWP(p)[((sg ^ (p & 7)) << 3) | so] = f2bf(acc[i8][j][r]);
        }
      }
    __syncthreads();
#pragma unroll
    for (int pp = 0; pp < 16; ++pp) {
      const int chunk = pp * 512 + tid;
      const int p = chunk >> 5, sg = chunk & 31;
      uint4 vv = *(const uint4*)&ROWP(p)[(sg ^ (p & 7)) << 3];
      *(uint4*)&kb[(size_t)(m0 + p) * 1024 + n0 + sg * 8] = vv;
    }
  } else {
    // V: p = c (head-local col), s = kv within 256-block
#pragma unroll
    for (int i8 = 0; i8 < 8; ++i8)
#pragma unroll
      for (int j = 0; j < 4; ++j) {
        const int p = wc * 64 + j * 16 + l15;
        const int s = wr * 128 + i8 * 16 + quad * 4;
        const int sg = s >> 3, so = s & 7;           // so = (quad&1)*4
        uint2 st;
        st.x = cvtpk(acc[i8][j][0], acc[i8][j][1]);
        st.y = cvtpk(acc[i8][j][2], acc[i8][j][3]);
        *(uint2*)&ROWP(p)[((sg ^ (p & 7)) << 3) | so] = st;
      }
    __syncthreads();
    const int bb_ = m0 >> 12;
    const int h0 = (n0 - 1024) >> 6;
#pragma unroll
    for (int pp = 0; pp < 16; ++pp) {
      const int chunk = pp * 512 + tid;
      const int p = chunk >> 5, sg = chunk & 31;
      uint4 vv = *(const uint4*)&ROWP(p)[(sg ^ (p & 7)) << 3];
      const size_t row = (size_t)((bb_ * 16 + h0 + (p >> 6)) * 64 + (p & 63));
      *(uint4*)&vTb[row * NKV_ + (m0 & 4095) + sg * 8] = vv;
    }
  }
#undef ROWP
#undef STAGE_A
#undef STAGE_B
#undef LDA2
#undef LDB2
#undef MF
}

// ---------------- out-proj GEMM: 64x128 tiles, tri-buffered counted-vmcnt pipeline ------
__global__ __launch_bounds__(256) void out_gemm(const u16* __restrict__ A,
                                                const u16* __restrict__ Bt,
                                                float* __restrict__ Cout,
                                                const float* __restrict__ bias) {
  __shared__ __align__(16) u16 As[3][64 * 32];    // 12 KB
  __shared__ __align__(16) u16 Bs[3][128 * 32];   // 24 KB
  const int tid = threadIdx.x;
  const int lane = tid & 63;
  const int w = tid >> 6;
  const int wr = w >> 1, wc = w & 1;           // wave covers 32M x 64N
  const int l15 = lane & 15, quad = lane >> 4;
  const int unit = blockIdx.x;
  const int m0 = (unit >> 3) * 64, n0 = (unit & 7) * 128;
  const int K = 1024, N = 1024;

  const u16* Ab = A + (size_t)m0 * K;
  const u16* Bb = Bt + (size_t)n0 * K;
  f32x4 acc[2][4] = {};

  const int ar = tid >> 2, ac = (tid & 3) << 3;          // A: 256 chunks, 1/thread
  const int q1 = w * 64 + lane, q2 = q1 + 256;           // B: 512 chunks, 2/thread
  const int br1 = q1 >> 2, bc1 = (q1 & 3) << 3;
  const int br2 = q2 >> 2, bc2 = (q2 & 3) << 3;

#define STG(bi, k0) do { \
    gload16(Ab + (size_t)ar * K + (k0) + ac, &As[bi][w * 512]); \
    gload16(Bb + (size_t)br1 * K + (k0) + bc1, &Bs[bi][w * 512]); \
    gload16(Bb + (size_t)br2 * K + (k0) + bc2, &Bs[bi][2048 + w * 512]); \
  } while (0)

  STG(0, 0);
  STG(1, 32);
  asm volatile("s_waitcnt vmcnt(3)" ::: "memory");   // STG(0) complete, STG(1) in flight
  __builtin_amdgcn_s_barrier();

  for (int it = 0; it < 32; ++it) {
    const int cur = it % 3;
    bf16x8 af[2], bfr[4];
#pragma unroll
    for (int i = 0; i < 2; ++i)
      af[i] = *(const bf16x8*)&As[cur][(wr * 32 + i * 16 + l15) * 32 + quad * 8];
#pragma unroll
    for (int j = 0; j < 4; ++j)
      bfr[j] = *(const bf16x8*)&Bs[cur][(wc * 64 + j * 16 + l15) * 32 + quad * 8];
    if (it + 2 < 32) STG((it + 2) % 3, (it + 2) * 32);
    __builtin_amdgcn_s_barrier();
    asm volatile("s_waitcnt lgkmcnt(0)" ::: "memory");
    __builtin_amdgcn_s_setprio(1);
#pragma unroll
    for (int i = 0; i < 2; ++i)
#pragma unroll
      for (int j = 0; j < 4; ++j)
        acc[i][j] = __builtin_amdgcn_mfma_f32_16x16x32_bf16(af[i], bfr[j], acc[i][j], 0, 0, 0);
    __builtin_amdgcn_s_setprio(0);
    if (it + 2 < 32)      { asm volatile("s_waitcnt vmcnt(3)" ::: "memory"); }
    else if (it + 2 == 32){ asm volatile("s_waitcnt vmcnt(0)" ::: "memory"); }
    __builtin_amdgcn_s_barrier();
  }
#undef STG

#pragma unroll
  for (int i = 0; i < 2; ++i)
#pragma unroll
    for (int j = 0; j < 4; ++j) {
      int col = n0 + wc * 64 + j * 16 + l15;
      float bv = bias[col];
#pragma unroll
      for (int r = 0; r < 4; ++r) {
        int row = m0 + wr * 32 + i * 16 + quad * 4 + r;
        Cout[(size_t)row * N + col] = acc[i][j][r] + bv;
      }
    }
}

// ---------------- flash attention + fused Q-projection (R13-proven) ---------------------
__global__ __launch_bounds__(256, 2) void attn_kernel(const u16* __restrict__ xb,
                                                      const u16* __restrict__ WqT,
                                                      const u16* __restrict__ kb,
                                                      const u16* __restrict__ vT,
                                                      u16* __restrict__ attn_out) {
  __shared__ __align__(16) u16 Ks[128 * 64];       // [kv][dh], 16B groups XOR-swizzled
  __shared__ __align__(16) u16 Vs[64 * 128];       // [dh][kv], XOR-swizzled (16 groups/row)
  __shared__ __align__(16) u32 P32[4 * 4 * 16 * 20]; // [w][t][q=l15][20]: wave-private pairs
  __shared__ float Lr[4][4][16];                   // [w][t][q] partial l

  const int tid = threadIdx.x;
  const int lane = tid & 63;
  const int w = tid >> 6;
  const int l15 = lane & 15, quad = lane >> 4;
  const int bh = blockIdx.x, b = bh >> 4, h = bh & 15;
  const int q0 = blockIdx.y * 64;

  const float SC = 0.125f * 1.44269504088896340736f;   // dh^-0.5 * log2(e)
  union { u16 s[8]; u32 u[4]; bf16x8 v; } qf[4][2];

  // ---- Q-projection prologue (double-buffered, R12-proven) ----
  {
    const u16* Axb = xb + (size_t)(b * NQ_ + q0) * 1024;     // 64 rows of x (bf16)
    const u16* Bwq = WqT + (size_t)(h * 64) * 1024;          // 64 Wq-columns
    const int c1 = tid, c2 = tid + 256;
    const int r1 = c1 >> 3, g1 = c1 & 7;
    const int r2 = c2 >> 3, g2 = c2 & 7;
    const size_t sO1 = (size_t)r1 * 1024 + (size_t)((g1 ^ (r1 & 7)) << 3);
    const size_t sO2 = (size_t)r2 * 1024 + (size_t)((g2 ^ (r2 & 7)) << 3);
    f32x4 qacc[4] = {};
    const int x7 = l15 & 7;

#define QSTG(dst, kk) do { \
      gload16(Axb + sO1 + (kk), &dst[w * 512]); \
      gload16(Axb + sO2 + (kk), &dst[2048 + w * 512]); \
      gload16(Bwq + sO1 + (kk), &dst[4096 + w * 512]); \
      gload16(Bwq + sO2 + (kk), &dst[6144 + w * 512]); \
    } while (0)

#define QSTEP(dst, kk, DOSTG, W4, W0) do { \
      bf16x8 af_[2], bfr_[4][2]; \
      _Pragma("unroll") \
      for (int kc = 0; kc < 2; ++kc) { \
        af_[kc] = *(const bf16x8*)&dst[(w * 16 + l15) * 64 + (((kc * 4 + quad) ^ x7) << 3)]; \
        _Pragma("unroll") \
        for (int j = 0; j < 4; ++j) \
          bfr_[j][kc] = *(const bf16x8*) \
            &dst[4096 + (j * 16 + l15) * 64 + (((kc * 4 + quad) ^ x7) << 3)]; \
      } \
      asm volatile("s_waitcnt lgkmcnt(0)" ::: "memory"); \
      __builtin_amdgcn_s_barrier(); \
      if (DOSTG) QSTG(dst, kk); \
      _Pragma("unroll") \
      for (int j = 0; j < 4; ++j) { \
        qacc[j] = __builtin_amdgcn_mfma_f32_16x16x32_bf16(af_[0], bfr_[j][0], qacc[j], 0, 0, 0); \
        qacc[j] = __builtin_amdgcn_mfma_f32_16x16x32_bf16(af_[1], bfr_[j][1], qacc[j], 0, 0, 0); \
      } \
      if (W4)      { asm volatile("s_waitcnt vmcnt(4)" ::: "memory"); } \
      else if (W0) { asm volatile("s_waitcnt vmcnt(0)" ::: "memory"); } \
      __builtin_amdgcn_s_barrier(); \
    } while (0)

    QSTG(Ks, 0);
    QSTG(Vs, 64);
    asm volatile("s_waitcnt vmcnt(4)" ::: "memory");   // Ks's 4 complete, Vs in flight
    __builtin_amdgcn_s_barrier();
#pragma unroll
    for (int i = 0; i < 16; i += 2) {
      QSTEP(Ks, (i + 2) * 64, (i + 2) < 16, (i + 2) < 16, (i + 2) == 16);
      QSTEP(Vs, (i + 3) * 64, (i + 3) < 16, (i + 3) < 16, 0);
    }
#undef QSTG
#undef QSTEP

    // bounce: P32 as 64x64 f32, col' = col ^ ((row&7)*8)
    float* Q64 = (float*)P32;
#pragma unroll
    for (int j = 0; j < 4; ++j)
#pragma unroll
      for (int r = 0; r < 4; ++r) {
        int row = w * 16 + quad * 4 + r;
        Q64[row * 64 + ((j * 16 + l15) ^ ((row & 7) * 8))] = qacc[j][r];
      }
    __syncthreads();
#pragma unroll
    for (int t = 0; t < 4; ++t)
#pragma unroll
      for (int kc = 0; kc < 2; ++kc) {
        const float* qp = Q64 + (t * 16 + l15) * 64 + (((kc * 4 + quad) ^ x7) * 8);
        f32x4 lo = *(const f32x4*)qp;
        f32x4 hi = *(const f32x4*)(qp + 4);
        qf[t][kc].u[0] = cvtpk(lo[0] * SC, lo[1] * SC);
        qf[t][kc].u[1] = cvtpk(lo[2] * SC, lo[3] * SC);
        qf[t][kc].u[2] = cvtpk(hi[0] * SC, hi[1] * SC);
        qf[t][kc].u[3] = cvtpk(hi[2] * SC, hi[3] * SC);
      }
    __syncthreads();   // all qf reads done before main loop reuses P32
  }

#define STAGEKV(j0) do { \
    _Pragma("unroll") \
    for (int i_ = 0; i_ < 4; ++i_) { \
      int s_ = i_ * 256 + tid; \
      int kr = s_ >> 3, kg = (s_ ^ kr) & 7; \
      gload16(kb + (size_t)(b * NKV_ + (j0) + kr) * 1024 + h * 64 + kg * 8, \
              &Ks[(i_ * 256 + w * 64) * 8]); \
      int vr = s_ >> 4, vg = (s_ ^ vr) & 15; \
      gload16(vT + (size_t)(bh * 64 + vr) * NKV_ + (j0) + vg * 8, \
              &Vs[(i_ * 256 + w * 64) * 8]); \
    } \
  } while (0)

  f32x4 Oacc[4][4] = {};
  float l_lane[4] = {0.f, 0.f, 0.f, 0.f};

  STAGEKV(0);                                // prologue: tile 0

  for (int it = 0; it < 32; ++it) {
    __syncthreads();                         // tile `it` staged (vmcnt drained per-wave)

    // fragment reads for tile `it` (this wave's complete K/V consumption)
    bf16x8 kf[2][2];
#pragma unroll
    for (int kvt = 0; kvt < 2; ++kvt)
#pragma unroll
      for (int kc = 0; kc < 2; ++kc)
        kf[kvt][kc] = *(const bf16x8*)
          &Ks[(w * 32 + kvt * 16 + l15) * 64 + (((kc * 4 + quad) ^ l15) & 7) * 8];
    bf16x8 vf[4];
#pragma unroll
    for (int d = 0; d < 4; ++d)
      vf[d] = *(const bf16x8*)
        &Vs[(d * 16 + l15) * 128 + (((w * 4 + quad) ^ l15) & 15) * 8];

    __syncthreads();                         // all waves done reading Ks/Vs

    if (it < 31) STAGEKV((it + 1) * 128);    // overwrite: overlaps full compute below

    f32x4 sacc[2][4] = {};
    __builtin_amdgcn_s_setprio(1);
#pragma unroll
    for (int kvt = 0; kvt < 2; ++kvt)
#pragma unroll
      for (int t = 0; t < 4; ++t)
#pragma unroll
        for (int kc = 0; kc < 2; ++kc)
          sacc[kvt][t] = __builtin_amdgcn_mfma_f32_16x16x32_bf16(
              kf[kvt][kc], qf[t][kc].v, sacc[kvt][t], 0, 0, 0);
    __builtin_amdgcn_s_setprio(0);

#pragma unroll
    for (int kvt = 0; kvt < 2; ++kvt)
#pragma unroll
      for (int t = 0; t < 4; ++t) {
        float p0 = __builtin_amdgcn_exp2f(sacc[kvt][t][0]);
        float p1 = __builtin_amdgcn_exp2f(sacc[kvt][t][1]);
        float p2 = __builtin_amdgcn_exp2f(sacc[kvt][t][2]);
        float p3 = __builtin_amdgcn_exp2f(sacc[kvt][t][3]);
        l_lane[t] += (p0 + p1) + (p2 + p3);
        uint2 pk; pk.x = cvtpk(p0, p1); pk.y = cvtpk(p2, p3);
        *(uint2*)&P32[((w * 4 + t) * 16 + l15) * 20 + kvt * 8 + quad * 2] = pk;
      }

    bf16x8 pf[4];
#pragma unroll
    for (int t = 0; t < 4; ++t)
      pf[t] = *(const bf16x8*)&P32[((w * 4 + t) * 16 + l15) * 20 + quad * 4];
    __builtin_amdgcn_s_setprio(1);
#pragma unroll
    for (int d = 0; d < 4; ++d)
#pragma unroll
      for (int t = 0; t < 4; ++t)
        Oacc[d][t] = __builtin_amdgcn_mfma_f32_16x16x32_bf16(vf[d], pf[t], Oacc[d][t],
                                                             0, 0, 0);
    __builtin_amdgcn_s_setprio(0);
  }
#undef STAGEKV

#pragma unroll
  for (int t = 0; t < 4; ++t) {
    l_lane[t] += __shfl_xor(l_lane[t], 16);
    l_lane[t] += __shfl_xor(l_lane[t], 32);
  }
  if (quad == 0) {
#pragma unroll
    for (int t = 0; t < 4; ++t) Lr[w][t][l15] = l_lane[t];
  }
  __syncthreads();                    // Lr ready; Ks/Vs/P32 all dead -> reduce buffers
  float inv = 1.0f / (Lr[0][w][l15] + Lr[1][w][l15] + Lr[2][w][l15] + Lr[3][w][l15]);

  float* R0 = (float*)Ks;             // 16 KB each; slice = 16*256 f32 = 16 KB
  float* R1 = (float*)Vs;
  float* R2 = (float*)P32;
  u16* ob = attn_out + (size_t)(b * NQ_ + q0 + w * 16 + l15) * INNER_ + h * 64;
  const int wi = quad * 64 + l15 * 4;

  // pass 1: slices d=0,1,2
#pragma unroll
  for (int t = 0; t < 4; ++t) {
    *(f32x4*)&R0[(w * 4 + t) * 256 + wi] = Oacc[0][t];
    *(f32x4*)&R1[(w * 4 + t) * 256 + wi] = Oacc[1][t];
    *(f32x4*)&R2[(w * 4 + t) * 256 + wi] = Oacc[2][t];
  }
  __syncthreads();
  {
    f32x4 r0 = *(const f32x4*)&R0[w * 256 + wi];
    f32x4 r1 = *(const f32x4*)&R1[w * 256 + wi];
    f32x4 r2 = *(const f32x4*)&R2[w * 256 + wi];
#pragma unroll
    for (int ww = 1; ww < 4; ++ww) {
      f32x4 c0 = *(const f32x4*)&R0[(ww * 4 + w) * 256 + wi];
      f32x4 c1 = *(const f32x4*)&R1[(ww * 4 + w) * 256 + wi];
      f32x4 c2 = *(const f32x4*)&R2[(ww * 4 + w) * 256 + wi];
#pragma unroll
      for (int e = 0; e < 4; ++e) { r0[e] += c0[e]; r1[e] += c1[e]; r2[e] += c2[e]; }
    }
    *(u32*)(ob + 0 * 16 + quad * 4)     = cvtpk(r0[0] * inv, r0[1] * inv);
    *(u32*)(ob + 0 * 16 + quad * 4 + 2) = cvtpk(r0[2] * inv, r0[3] * inv);
    *(u32*)(ob + 1 * 16 + quad * 4)     = cvtpk(r1[0] * inv, r1[1] * inv);
    *(u32*)(ob + 1 * 16 + quad * 4 + 2) = cvtpk(r1[2] * inv, r1[3] * inv);
    *(u32*)(ob + 2 * 16 + quad * 4)     = cvtpk(r2[0] * inv, r2[1] * inv);
    *(u32*)(ob + 2 * 16 + quad * 4 + 2) = cvtpk(r2[2] * inv, r2[3] * inv);
  }
  __syncthreads();
  // pass 2: slice d=3
#pragma unroll
  for (int t = 0; t < 4; ++t)
    *(f32x4*)&R0[(w * 4 + t) * 256 + wi] = Oacc[3][t];
  __syncthreads();
  {
    f32x4 r = *(const f32x4*)&R0[w * 256 + wi];
#pragma unroll
    for (int ww = 1; ww < 4; ++ww) {
      f32x4 c = *(const f32x4*)&R0[(ww * 4 + w) * 256 + wi];
#pragma unroll
      for (int e = 0; e < 4; ++e) r[e] += c[e];
    }
    *(u32*)(ob + 3 * 16 + quad * 4)     = cvtpk(r[0] * inv, r[1] * inv);
    *(u32*)(ob + 3 * 16 + quad * 4 + 2) = cvtpk(r[2] * inv, r[3] * inv);
  }
}

// ---------------- driver ----------------
extern "C" void kernel_launch(void* const* d_in, const int* in_sizes, int n_in,
                              void* d_out, int out_size, void* d_ws, size_t ws_size,
                              hipStream_t stream) {
  const float* x    = (const float*)d_in[0];
  const float* ctx  = (const float*)d_in[1];
  const float* Wq   = (const float*)d_in[2];
  const float* Wkv  = (const float*)d_in[3];
  const float* Wout = (const float*)d_in[4];
  const float* bout = (const float*)d_in[5];

  char* ws = (char*)d_ws;
  u16* xb    = (u16*)(ws + (size_t)( 0u << 20));  // 4 MB  [live through attn prologue]
  u16* ctxb  = (u16*)(ws + (size_t)( 4u << 20));  // 16 MB [dead after kv_gemm]
  u16* WqT   = (u16*)(ws + (size_t)(20u << 20));  // 2 MB  [live through attn prologue]
  u16* WkvT  = (u16*)(ws + (size_t)(22u << 20));  // 4 MB
  u16* WoutT = (u16*)(ws + (size_t)(26u << 20));  // 2 MB
  u16* ab    = (u16*)(ws + (size_t)(28u << 20));  // 4 MB  [old qb slot; NOT aliasing xb]
  u16* kb    = (u16*)(ws + (size_t)(32u << 20));  // 16 MB (K row-major bf16)
  u16* vTb   = (u16*)(ws + (size_t)(48u << 20));  // 16 MB (V transposed [bh*64+dh][NKV])

  // casts + weight transposes in one dispatch (64x64 transpose tiles, fat casts)
  prep<<<1664, 256, 0, stream>>>(x, ctx, Wq, Wkv, Wout, xb, ctxb, WqT, WkvT, WoutT);
  // kv projection: 256 blocks of 256x256, 8-phase + LDS-bounce coalesced epilogue
  kv_gemm<<<256, 512, 0, stream>>>(ctxb, WkvT, kb, vTb);
  // fused q-projection + softmax attention: 512 blocks x 256 threads
  attn_kernel<<<dim3(32, 16), 256, 0, stream>>>(xb, WqT, kb, vTb, ab);
  // out = attn Wout + b_out : fp32, 256 blocks, tri-buffered pipeline
  out_gemm<<<256, 256, 0, stream>>>(ab, WoutT, (float*)d_out, bout);
}